// Round 6
// baseline (334.174 us; speedup 1.0000x reference)
//
#include <hip/hip_runtime.h>
#include <hip/hip_bf16.h>

typedef __attribute__((ext_vector_type(8))) short bf16x8;
typedef __attribute__((ext_vector_type(4))) float f32x4;
typedef unsigned short ushort_t;

#define HID 2048
#define QKVN 6144
#define SEQ 2048
#define NH 16
#define HD 128
#define QB 128
#define KVB 64

#define GLOBAL_AS __attribute__((address_space(1)))
#define LDS_AS __attribute__((address_space(3)))

__device__ __forceinline__ void gload_lds16(const ushort_t* g, ushort_t* l) {
    __builtin_amdgcn_global_load_lds((const GLOBAL_AS unsigned int*)g,
                                     (LDS_AS unsigned int*)l, 16, 0, 0);
}

__device__ __forceinline__ ushort_t f2b(float f) {
    union { float f; unsigned int u; } x; x.f = f;
    unsigned int r = x.u + 0x7fffu + ((x.u >> 16) & 1u);  // RNE
    return (ushort_t)(r >> 16);
}

#define BARX() asm volatile("s_barrier" ::: "memory")
#define VMC2() asm volatile("s_waitcnt vmcnt(2)" ::: "memory")
#define VMC0() asm volatile("s_waitcnt vmcnt(0)" ::: "memory")

// ---------------- cast fp32 -> bf16 (vectorized) ----------------
__global__ __launch_bounds__(256) void castbf(const float* __restrict__ in,
                                              ushort_t* __restrict__ out, int n) {
    int i = (blockIdx.x * 256 + threadIdx.x) * 8;
    if (i >= n) return;
    float4 a = *(const float4*)(in + i);
    float4 b = *(const float4*)(in + i + 4);
    union { ushort_t u[8]; uint4 v; } r;
    r.u[0] = f2b(a.x); r.u[1] = f2b(a.y); r.u[2] = f2b(a.z); r.u[3] = f2b(a.w);
    r.u[4] = f2b(b.x); r.u[5] = f2b(b.y); r.u[6] = f2b(b.z); r.u[7] = f2b(b.w);
    *(uint4*)(out + i) = r.v;
}

// ------------- transpose + cast: fp32 K x N  ->  bf16 N x K -------------
__global__ __launch_bounds__(256) void transcast(const float* __restrict__ in,
                                                 ushort_t* __restrict__ out,
                                                 int Kd, int Nd) {
    __shared__ float tile[32][33];
    int tx = threadIdx.x & 31, ty = threadIdx.x >> 5;
    int n0 = blockIdx.x * 32, k0 = blockIdx.y * 32;
    for (int j = 0; j < 4; j++)
        tile[ty + 8 * j][tx] = in[(size_t)(k0 + ty + 8 * j) * Nd + n0 + tx];
    __syncthreads();
    for (int j = 0; j < 4; j++)
        out[(size_t)(n0 + ty + 8 * j) * Kd + k0 + tx] = f2b(tile[tx][ty + 8 * j]);
}

// ------------- transpose V region of qkv (bf16) -> vT[b][h][d][s] -------------
__global__ __launch_bounds__(256) void transV(const ushort_t* __restrict__ qkvb,
                                              ushort_t* __restrict__ vT) {
    __shared__ ushort_t tile[32][33];
    int tx = threadIdx.x & 31, ty = threadIdx.x >> 5;
    int s0 = blockIdx.x * 32, d0 = blockIdx.y * 32;
    int bh = blockIdx.z; int b = bh >> 4, h = bh & 15;
    for (int j = 0; j < 4; j++)
        tile[ty + 8 * j][tx] =
            qkvb[(size_t)(b * SEQ + s0 + ty + 8 * j) * QKVN + 2 * HID + h * HD + d0 + tx];
    __syncthreads();
    for (int j = 0; j < 4; j++)
        vT[((size_t)bh * HD + d0 + ty + 8 * j) * SEQ + s0 + tx] = tile[tx][ty + 8 * j];
}

// ------------- GEMM 256x256, 8-phase (T2+T3+T4+T5), BK=64, 8 waves, min LDS reads -------------
// C(MxN) = A(MxK,bf16) * BT(NxK,bf16)^T.
// PHASE_A(buf,kk): read 4 B-frags (both B subs) + 4 A-frags (Asub0) -> 16 MFMA (acc rows 0-3).
// PHASE_B(buf,kk): read 4 A-frags (Asub1), reuse bfr regs            -> 16 MFMA (acc rows 4-7).
// Each fragment is ds_read exactly once per K-tile: 24 reads/K-tile/wave (was 48).
// Stage slots (verified no write-while-read; vmcnt(2) at ph3/ph7 drains next-needed buf):
//   ph0: B(1,0,ko) B(1,1,ko) | ph1: A(1,1,ko) | ph3: A(0,0,ke2)+VMC2 |
//   ph4: B(0,0,ke2) B(0,1,ke2) | ph5: A(0,1,ke2) | ph7: A(1,0,ko2)+VMC2
template <bool OUT_BF16>
__global__ __launch_bounds__(512, 1) void gemm8p(const ushort_t* __restrict__ A,
                                                 const ushort_t* __restrict__ BT,
                                                 void* __restrict__ C,
                                                 int M, int N, int K,
                                                 int scale_cols, float scale) {
    __shared__ __align__(16) ushort_t As[2][2][128 * 64];  // 64 KB
    __shared__ __align__(16) ushort_t Bs[2][2][128 * 64];  // 64 KB

    const int t = threadIdx.x;
    const int l = t & 63, w = t >> 6;
    const int wm = w >> 2, wn = w & 3;          // 2 x 4 waves
    const int lr = l & 15, lg = l >> 4;
    const int sw = (lr & 7) << 4;

    // XCD-aware bijective swizzle (grid % 8 == 0 for all our shapes)
    const int nwg = gridDim.x;
    const int cpx = nwg >> 3;
    const int swb = (blockIdx.x & 7) * cpx + (blockIdx.x >> 3);
    const int NTN = N >> 8;
    const int m0 = (swb / NTN) << 8, n0 = (swb % NTN) << 8;

    const int NKT = K >> 6;
    const int NIT = NKT >> 1;

    f32x4 acc[8][4] = {};
    bf16x8 bfr[4];

#define STAGE_A(BUF, SUB, KT)                                                      \
    do {                                                                           \
        _Pragma("unroll") for (int sx = 0; sx < 2; sx++) {                         \
            const int i_ = sx * 512 + t;                                           \
            const int rs_ = i_ >> 3;                                               \
            const int grow_ = m0 + ((rs_ >> 6) << 7) + ((SUB) << 6) + (rs_ & 63);  \
            const int gcol_ = ((KT) << 6) + (((i_ & 7) ^ (rs_ & 7)) << 3);         \
            gload_lds16(A + (size_t)grow_ * K + gcol_, &As[BUF][SUB][i_ * 8]);     \
        }                                                                          \
    } while (0)
#define STAGE_B(BUF, SUB, KT)                                                      \
    do {                                                                           \
        _Pragma("unroll") for (int sx = 0; sx < 2; sx++) {                         \
            const int i_ = sx * 512 + t;                                           \
            const int rs_ = i_ >> 3;                                               \
            const int grow_ = n0 + ((rs_ >> 5) << 6) + ((SUB) << 5) + (rs_ & 31);  \
            const int gcol_ = ((KT) << 6) + (((i_ & 7) ^ (rs_ & 7)) << 3);         \
            gload_lds16(BT + (size_t)grow_ * K + gcol_, &Bs[BUF][SUB][i_ * 8]);    \
        }                                                                          \
    } while (0)

#define PHASE_A(BUF, KK, STAGES)                                                    \
    {                                                                               \
        bf16x8 af[4];                                                               \
        const char* aB_ = (const char*)&As[BUF][0][0];                              \
        const char* b0_ = (const char*)&Bs[BUF][0][0];                              \
        const char* b1_ = (const char*)&Bs[BUF][1][0];                              \
        const int co_ = ((KK) * 64 + lg * 16) ^ sw;                                 \
        _Pragma("unroll") for (int nn = 0; nn < 2; nn++) {                          \
            bfr[nn]     = *(const bf16x8*)(b0_ + (wn * 32 + nn * 16 + lr) * 128 + co_); \
            bfr[nn + 2] = *(const bf16x8*)(b1_ + (wn * 32 + nn * 16 + lr) * 128 + co_); \
        }                                                                           \
        _Pragma("unroll") for (int mi = 0; mi < 4; mi++)                            \
            af[mi] = *(const bf16x8*)(aB_ + (wm * 64 + mi * 16 + lr) * 128 + co_);  \
        STAGES;                                                                     \
        BARX();                                                                     \
        __builtin_amdgcn_s_setprio(1);                                              \
        _Pragma("unroll") for (int mi = 0; mi < 4; mi++)                            \
            _Pragma("unroll") for (int nn = 0; nn < 4; nn++)                        \
                acc[mi][nn] = __builtin_amdgcn_mfma_f32_16x16x32_bf16(              \
                    af[mi], bfr[nn], acc[mi][nn], 0, 0, 0);                         \
        __builtin_amdgcn_s_setprio(0);                                              \
        BARX();                                                                     \
    }

#define PHASE_B(BUF, KK, STAGES)                                                    \
    {                                                                               \
        bf16x8 af[4];                                                               \
        const char* aB_ = (const char*)&As[BUF][1][0];                              \
        const int co_ = ((KK) * 64 + lg * 16) ^ sw;                                 \
        _Pragma("unroll") for (int mi = 0; mi < 4; mi++)                            \
            af[mi] = *(const bf16x8*)(aB_ + (wm * 64 + mi * 16 + lr) * 128 + co_);  \
        STAGES;                                                                     \
        BARX();                                                                     \
        __builtin_amdgcn_s_setprio(1);                                              \
        _Pragma("unroll") for (int mi = 0; mi < 4; mi++)                            \
            _Pragma("unroll") for (int nn = 0; nn < 4; nn++)                        \
                acc[4 + mi][nn] = __builtin_amdgcn_mfma_f32_16x16x32_bf16(          \
                    af[mi], bfr[nn], acc[4 + mi][nn], 0, 0, 0);                     \
        __builtin_amdgcn_s_setprio(0);                                              \
        BARX();                                                                     \
    }

    // prologue: buf0 all 4 subs (kt0) + buf1.Asub0 (kt1); drain buf0, keep A10 in flight
    STAGE_A(0, 0, 0); STAGE_A(0, 1, 0); STAGE_B(0, 0, 0); STAGE_B(0, 1, 0);
    STAGE_A(1, 0, 1);
    VMC2();
    BARX();

    for (int it = 0; it < NIT; it++) {
        const int ko  = 2 * it + 1;                 // buf1 data consumed this iter
        const int ke2 = min(2 * it + 2, NKT - 1);   // buf0 next (tail: dead re-stage)
        const int ko2 = min(2 * it + 3, NKT - 1);   // buf1 next
        PHASE_A(0, 0, { STAGE_B(1, 0, ko); STAGE_B(1, 1, ko); });
        PHASE_B(0, 0, { STAGE_A(1, 1, ko); });
        PHASE_A(0, 1, {});
        PHASE_B(0, 1, { STAGE_A(0, 0, ke2); VMC2(); });
        PHASE_A(1, 0, { STAGE_B(0, 0, ke2); STAGE_B(0, 1, ke2); });
        PHASE_B(1, 0, { STAGE_A(0, 1, ke2); });
        PHASE_A(1, 1, {});
        PHASE_B(1, 1, { STAGE_A(1, 0, ko2); VMC2(); });
    }
    VMC0();

#undef PHASE_A
#undef PHASE_B
#undef STAGE_A
#undef STAGE_B

    // epilogue
#pragma unroll
    for (int mq = 0; mq < 2; mq++)
#pragma unroll
        for (int mi = 0; mi < 4; mi++)
#pragma unroll
            for (int nn = 0; nn < 4; nn++) {
                const int row = m0 + wm * 128 + mq * 64 + mi * 16 + lg * 4;
                const int col = n0 + wn * 64 + (nn >> 1) * 32 + (nn & 1) * 16 + lr;
                const float sc = (col < scale_cols) ? scale : 1.0f;
                const f32x4 v = acc[mq * 4 + mi][nn];
#pragma unroll
                for (int j = 0; j < 4; j++) {
                    if (OUT_BF16)
                        ((ushort_t*)C)[(size_t)(row + j) * N + col] = f2b(v[j] * sc);
                    else
                        ((float*)C)[(size_t)(row + j) * N + col] = v[j] * sc;
                }
            }
}

// ------------- flash attention v3: 8 waves x 16 q-rows, paired q-tiles, dbuf gload_lds -------------
__global__ __launch_bounds__(512, 1) void attn_fwd3(const ushort_t* __restrict__ qkvb,
                                                    const ushort_t* __restrict__ vT,
                                                    ushort_t* __restrict__ attnb) {
    __shared__ __align__(16) ushort_t Ks[2][64 * 128];
    __shared__ __align__(16) ushort_t Vs[2][128 * 64];
    __shared__ __align__(16) ushort_t Ps[8][16 * 64];

    const int t = threadIdx.x;
    const int l = t & 63, w = t >> 6;
    const int lr = l & 15, lg = l >> 4;
    const int pr = blockIdx.x, h = blockIdx.y, b = blockIdx.z;

    const ushort_t* kg = qkvb + (size_t)(b * SEQ) * QKVN + HID + h * HD;
    const ushort_t* vg = vT + (size_t)(b * NH + h) * HD * SEQ;

    char* PsB = (char*)Ps[w];
    const int pssz = ((lr & 7) ^ ((lr >> 3) << 1)) << 4;

    const int kcA = 2 * w, kcB = 2 * w + 1;
    const int krA = 8 * w + (l >> 4), krB = krA + 4;
    const int kcolA = ((l & 15) ^ (l >> 4)) << 3;
    const int kcolB = ((l & 15) ^ (4 + (l >> 4))) << 3;
    const int vrA = 16 * w + (l >> 3), vrB = vrA + 8;
    const int vcol = ((l & 7) ^ (l >> 3)) << 3;

    for (int seg = 0; seg < 2; seg++) {
        const int qt = (seg == 0) ? pr : 15 - pr;
        const int q0 = qt * QB;
        const int q0w = q0 + w * 16;
        const int NT = (q0 + QB) / KVB;

        bf16x8 qf[4];
        {
            const ushort_t* qb = qkvb + (size_t)(b * SEQ + q0w + lr) * QKVN + h * HD + lg * 8;
#pragma unroll
            for (int kc = 0; kc < 4; kc++) qf[kc] = *(const bf16x8*)(qb + kc * 32);
        }
        f32x4 o[8] = {};
        float m[4] = {-3e38f, -3e38f, -3e38f, -3e38f};
        float ls[4] = {0.f, 0.f, 0.f, 0.f};

        __syncthreads();
        gload_lds16(kg + (size_t)krA * QKVN + kcolA, &Ks[0][kcA * 512 + l * 8]);
        gload_lds16(kg + (size_t)krB * QKVN + kcolB, &Ks[0][kcB * 512 + l * 8]);
        gload_lds16(vg + (size_t)vrA * SEQ + vcol,   &Vs[0][kcA * 512 + l * 8]);
        gload_lds16(vg + (size_t)vrB * SEQ + vcol,   &Vs[0][kcB * 512 + l * 8]);

        for (int kt = 0; kt < NT; kt++) {
            const int kv0 = kt * KVB;
            __syncthreads();
            if (kt + 1 < NT) {
                const int nb = (kt + 1) & 1;
                const int nkv = kv0 + KVB;
                gload_lds16(kg + (size_t)(nkv + krA) * QKVN + kcolA, &Ks[nb][kcA * 512 + l * 8]);
                gload_lds16(kg + (size_t)(nkv + krB) * QKVN + kcolB, &Ks[nb][kcB * 512 + l * 8]);
                gload_lds16(vg + (size_t)vrA * SEQ + nkv + vcol,     &Vs[nb][kcA * 512 + l * 8]);
                gload_lds16(vg + (size_t)vrB * SEQ + nkv + vcol,     &Vs[nb][kcB * 512 + l * 8]);
            }
            if (kv0 > q0w + 15) continue;
            const char* KsB = (const char*)Ks[kt & 1];
            const char* VsB = (const char*)Vs[kt & 1];

            f32x4 s[4];
            const int rs = (lr & 7) << 4;
#pragma unroll
            for (int nf = 0; nf < 4; nf++) {
                const int r = nf * 16 + lr;
                s[nf] = (f32x4){0.f, 0.f, 0.f, 0.f};
#pragma unroll
                for (int kc = 0; kc < 4; kc++) {
                    bf16x8 kf = *(const bf16x8*)(KsB + r * 256 + ((kc * 64 + lg * 16) ^ rs));
                    s[nf] = __builtin_amdgcn_mfma_f32_16x16x32_bf16(qf[kc], kf, s[nf], 0, 0, 0);
                }
            }

            const bool diag = (kv0 + 63 > q0w);
            float tm[4];
#pragma unroll
            for (int j = 0; j < 4; j++) {
                if (diag) {
                    const int qpos = q0w + lg * 4 + j;
#pragma unroll
                    for (int nf = 0; nf < 4; nf++)
                        if (kv0 + nf * 16 + lr > qpos) s[nf][j] = -3e38f;
                }
                tm[j] = fmaxf(fmaxf(s[0][j], s[1][j]), fmaxf(s[2][j], s[3][j]));
#pragma unroll
                for (int mk = 1; mk < 16; mk <<= 1)
                    tm[j] = fmaxf(tm[j], __shfl_xor(tm[j], mk, 64));
            }

            float grow = fmaxf(fmaxf(tm[0] - m[0], tm[1] - m[1]),
                               fmaxf(tm[2] - m[2], tm[3] - m[3]));
            if (!__all(grow <= 8.0f)) {
#pragma unroll
                for (int j = 0; j < 4; j++) {
                    const float mn = fmaxf(m[j], tm[j]);
                    const float fac = exp2f((m[j] - mn) * 1.44269504f);
                    m[j] = mn; ls[j] *= fac;
#pragma unroll
                    for (int nf2 = 0; nf2 < 8; nf2++) o[nf2][j] *= fac;
                }
            }

#pragma unroll
            for (int j = 0; j < 4; j++) {
                const int row = lg * 4 + j;
                const int rsz = ((row & 7) ^ ((row >> 3) << 1)) << 4;
                float psum = 0.f;
#pragma unroll
                for (int nf = 0; nf < 4; nf++) {
                    float p = exp2f((s[nf][j] - m[j]) * 1.44269504f);
                    psum += p;
                    union { float f; unsigned u; } cv; cv.f = p;
                    *(ushort_t*)(PsB + row * 128 + ((nf * 32 + lr * 2) ^ rsz)) = (ushort_t)(cv.u >> 16);
                }
                ls[j] += psum;
            }

            bf16x8 pa0 = *(const bf16x8*)(PsB + lr * 128 + ((lg * 16) ^ pssz));
            bf16x8 pa1 = *(const bf16x8*)(PsB + lr * 128 + ((64 + lg * 16) ^ pssz));
#pragma unroll
            for (int nf2 = 0; nf2 < 8; nf2++) {
                const int vr2 = nf2 * 16 + lr;
                bf16x8 vb0 = *(const bf16x8*)(VsB + vr2 * 128 + ((lg * 16) ^ rs));
                bf16x8 vb1 = *(const bf16x8*)(VsB + vr2 * 128 + ((64 + lg * 16) ^ rs));
                o[nf2] = __builtin_amdgcn_mfma_f32_16x16x32_bf16(pa0, vb0, o[nf2], 0, 0, 0);
                o[nf2] = __builtin_amdgcn_mfma_f32_16x16x32_bf16(pa1, vb1, o[nf2], 0, 0, 0);
            }
        }

        float inv[4];
#pragma unroll
        for (int j = 0; j < 4; j++) {
            float sum = ls[j];
#pragma unroll
            for (int mk = 1; mk < 16; mk <<= 1) sum += __shfl_xor(sum, mk, 64);
            inv[j] = 1.0f / sum;
        }
        ushort_t* ob = attnb + (size_t)(b * SEQ + q0w) * HID + h * HD;
#pragma unroll
        for (int nf2 = 0; nf2 < 8; nf2++)
#pragma unroll
            for (int j = 0; j < 4; j++)
                ob[(size_t)(lg * 4 + j) * HID + nf2 * 16 + lr] = f2b(o[nf2][j] * inv[j]);
    }
}

extern "C" void kernel_launch(void* const* d_in, const int* in_sizes, int n_in,
                              void* d_out, int out_size, void* d_ws, size_t ws_size,
                              hipStream_t stream) {
    const float* x     = (const float*)d_in[0];
    const float* w_qkv = (const float*)d_in[1];
    const float* w_out = (const float*)d_in[2];
    float* out = (float*)d_out;

    char* ws = (char*)d_ws;
    ushort_t* xb    = (ushort_t*)(ws);                 // 4096x2048 bf16
    ushort_t* wqkvT = (ushort_t*)(ws + 16777216);      // 6144x2048 bf16
    ushort_t* woutT = (ushort_t*)(ws + 41943040);      // 2048x2048 bf16
    ushort_t* qkvb  = (ushort_t*)(ws + 50331648);      // 4096x6144 bf16
    ushort_t* vT    = (ushort_t*)(ws + 100663296);     // [b][h][d][s] bf16
    ushort_t* attnb = (ushort_t*)(ws + 117440512);     // 4096x2048 bf16

    const int M = 2 * SEQ;  // 4096

    castbf<<<(M * HID) / (256 * 8), 256, 0, stream>>>(x, xb, M * HID);
    transcast<<<dim3(QKVN / 32, HID / 32), 256, 0, stream>>>(w_qkv, wqkvT, HID, QKVN);
    transcast<<<dim3(HID / 32, HID / 32), 256, 0, stream>>>(w_out, woutT, HID, HID);

    // qkv = x @ w_qkv, Q pre-scaled by 1/sqrt(HD); 8-phase 256^2 GEMM
    gemm8p<true><<<(M / 256) * (QKVN / 256), 512, 0, stream>>>(
        xb, wqkvT, qkvb, M, QKVN, HID, HID, 0.08838834764831845f);

    transV<<<dim3(SEQ / 32, HD / 32, 2 * NH), 256, 0, stream>>>(qkvb, vT);

    attn_fwd3<<<dim3(8, NH, 2), 512, 0, stream>>>(qkvb, vT, attnb);

    gemm8p<false><<<(M / 256) * (HID / 256), 512, 0, stream>>>(
        attnb, woutT, out, M, HID, HID, 0, 1.0f);
}

// Round 7
// 288.590 us; speedup vs baseline: 1.1580x; 1.1580x over previous
//
#include <hip/hip_runtime.h>
#include <hip/hip_bf16.h>

typedef __attribute__((ext_vector_type(8))) short bf16x8;
typedef __attribute__((ext_vector_type(4))) float f32x4;
typedef unsigned short ushort_t;

#define HID 2048
#define QKVN 6144
#define SEQ 2048
#define NH 16
#define HD 128
#define QB 128
#define KVB 64

#define GLOBAL_AS __attribute__((address_space(1)))
#define LDS_AS __attribute__((address_space(3)))
typedef LDS_AS const char lds_char;

__device__ __forceinline__ void gload_lds16(const ushort_t* g, ushort_t* l) {
    __builtin_amdgcn_global_load_lds((const GLOBAL_AS unsigned int*)g,
                                     (LDS_AS unsigned int*)l, 16, 0, 0);
}

// inline-asm ds_read_b128: opaque to SIInsertWaitcnts' LDS-DMA alias check,
// so no compiler-inserted vmcnt drain lands in front of it (rule 18 discipline:
// we supply lgkmcnt(0)+sched_barrier(0) ourselves before consuming).
__device__ __forceinline__ bf16x8 dsr128(lds_char* p) {
    bf16x8 r;
    asm volatile("ds_read_b128 %0, %1" : "=v"(r) : "v"(p));
    return r;
}

__device__ __forceinline__ ushort_t f2b(float f) {
    union { float f; unsigned int u; } x; x.f = f;
    unsigned int r = x.u + 0x7fffu + ((x.u >> 16) & 1u);  // RNE
    return (ushort_t)(r >> 16);
}

#define BARX() asm volatile("s_barrier" ::: "memory")
#define LGKM0() asm volatile("s_waitcnt lgkmcnt(0)" ::: "memory")
#define VMC2() asm volatile("s_waitcnt vmcnt(2)" ::: "memory")
#define VMC0() asm volatile("s_waitcnt vmcnt(0)" ::: "memory")

// ---------------- cast fp32 -> bf16 (vectorized) ----------------
__global__ __launch_bounds__(256) void castbf(const float* __restrict__ in,
                                              ushort_t* __restrict__ out, int n) {
    int i = (blockIdx.x * 256 + threadIdx.x) * 8;
    if (i >= n) return;
    float4 a = *(const float4*)(in + i);
    float4 b = *(const float4*)(in + i + 4);
    union { ushort_t u[8]; uint4 v; } r;
    r.u[0] = f2b(a.x); r.u[1] = f2b(a.y); r.u[2] = f2b(a.z); r.u[3] = f2b(a.w);
    r.u[4] = f2b(b.x); r.u[5] = f2b(b.y); r.u[6] = f2b(b.z); r.u[7] = f2b(b.w);
    *(uint4*)(out + i) = r.v;
}

// ------------- transpose + cast: fp32 K x N  ->  bf16 N x K -------------
__global__ __launch_bounds__(256) void transcast(const float* __restrict__ in,
                                                 ushort_t* __restrict__ out,
                                                 int Kd, int Nd) {
    __shared__ float tile[32][33];
    int tx = threadIdx.x & 31, ty = threadIdx.x >> 5;
    int n0 = blockIdx.x * 32, k0 = blockIdx.y * 32;
    for (int j = 0; j < 4; j++)
        tile[ty + 8 * j][tx] = in[(size_t)(k0 + ty + 8 * j) * Nd + n0 + tx];
    __syncthreads();
    for (int j = 0; j < 4; j++)
        out[(size_t)(n0 + ty + 8 * j) * Kd + k0 + tx] = f2b(tile[tx][ty + 8 * j]);
}

// ------------- transpose V region of qkv (bf16) -> vT[b][h][d][s] -------------
__global__ __launch_bounds__(256) void transV(const ushort_t* __restrict__ qkvb,
                                              ushort_t* __restrict__ vT) {
    __shared__ ushort_t tile[32][33];
    int tx = threadIdx.x & 31, ty = threadIdx.x >> 5;
    int s0 = blockIdx.x * 32, d0 = blockIdx.y * 32;
    int bh = blockIdx.z; int b = bh >> 4, h = bh & 15;
    for (int j = 0; j < 4; j++)
        tile[ty + 8 * j][tx] =
            qkvb[(size_t)(b * SEQ + s0 + ty + 8 * j) * QKVN + 2 * HID + h * HD + d0 + tx];
    __syncthreads();
    for (int j = 0; j < 4; j++)
        vT[((size_t)bh * HD + d0 + ty + 8 * j) * SEQ + s0 + tx] = tile[tx][ty + 8 * j];
}

// ------------- GEMM 256x256, 8-phase (T2+T3+T4+T5), BK=64, 8 waves, asm ds_read -------------
// C(MxN) = A(MxK,bf16) * BT(NxK,bf16)^T.
// PHASE_A(buf,kk): asm-read 4 B-frags + 4 A-frags(Asub0) -> 16 MFMA (acc rows 0-3).
// PHASE_B(buf,kk): asm-read 4 A-frags(Asub1), reuse bfr  -> 16 MFMA (acc rows 4-7).
// Per phase: reads, stages, s_barrier, lgkmcnt(0), sched_barrier(0), setprio+MFMA, s_barrier.
// Stage slots identical to r6 (verified drain trace): counted vmcnt(2) once per K-tile.
template <bool OUT_BF16>
__global__ __launch_bounds__(512, 1) void gemm8p(const ushort_t* __restrict__ A,
                                                 const ushort_t* __restrict__ BT,
                                                 void* __restrict__ C,
                                                 int M, int N, int K,
                                                 int scale_cols, float scale) {
    __shared__ __align__(16) ushort_t As[2][2][128 * 64];  // 64 KB
    __shared__ __align__(16) ushort_t Bs[2][2][128 * 64];  // 64 KB

    const int t = threadIdx.x;
    const int l = t & 63, w = t >> 6;
    const int wm = w >> 2, wn = w & 3;          // 2 x 4 waves
    const int lr = l & 15, lg = l >> 4;
    const int sw = (lr & 7) << 4;

    // XCD-aware bijective swizzle (grid % 8 == 0 for all our shapes)
    const int nwg = gridDim.x;
    const int cpx = nwg >> 3;
    const int swb = (blockIdx.x & 7) * cpx + (blockIdx.x >> 3);
    const int NTN = N >> 8;
    const int m0 = (swb / NTN) << 8, n0 = (swb % NTN) << 8;

    const int NKT = K >> 6;
    const int NIT = NKT >> 1;

    f32x4 acc[8][4] = {};
    bf16x8 bfr[4];

#define STAGE_A(BUF, SUB, KT)                                                      \
    do {                                                                           \
        _Pragma("unroll") for (int sx = 0; sx < 2; sx++) {                         \
            const int i_ = sx * 512 + t;                                           \
            const int rs_ = i_ >> 3;                                               \
            const int grow_ = m0 + ((rs_ >> 6) << 7) + ((SUB) << 6) + (rs_ & 63);  \
            const int gcol_ = ((KT) << 6) + (((i_ & 7) ^ (rs_ & 7)) << 3);         \
            gload_lds16(A + (size_t)grow_ * K + gcol_, &As[BUF][SUB][i_ * 8]);     \
        }                                                                          \
    } while (0)
#define STAGE_B(BUF, SUB, KT)                                                      \
    do {                                                                           \
        _Pragma("unroll") for (int sx = 0; sx < 2; sx++) {                         \
            const int i_ = sx * 512 + t;                                           \
            const int rs_ = i_ >> 3;                                               \
            const int grow_ = n0 + ((rs_ >> 5) << 6) + ((SUB) << 5) + (rs_ & 31);  \
            const int gcol_ = ((KT) << 6) + (((i_ & 7) ^ (rs_ & 7)) << 3);         \
            gload_lds16(BT + (size_t)grow_ * K + gcol_, &Bs[BUF][SUB][i_ * 8]);    \
        }                                                                          \
    } while (0)

#define PHASE_A(BUF, KK, STAGES)                                                    \
    {                                                                               \
        bf16x8 af[4];                                                               \
        lds_char* aB_ = (lds_char*)&As[BUF][0][0];                                  \
        lds_char* b0_ = (lds_char*)&Bs[BUF][0][0];                                  \
        lds_char* b1_ = (lds_char*)&Bs[BUF][1][0];                                  \
        const int co_ = ((KK) * 64 + lg * 16) ^ sw;                                 \
        bfr[0] = dsr128(b0_ + (wn * 32 + lr) * 128 + co_);                          \
        bfr[1] = dsr128(b0_ + (wn * 32 + 16 + lr) * 128 + co_);                     \
        bfr[2] = dsr128(b1_ + (wn * 32 + lr) * 128 + co_);                          \
        bfr[3] = dsr128(b1_ + (wn * 32 + 16 + lr) * 128 + co_);                     \
        _Pragma("unroll") for (int mi = 0; mi < 4; mi++)                            \
            af[mi] = dsr128(aB_ + (wm * 64 + mi * 16 + lr) * 128 + co_);            \
        STAGES;                                                                     \
        BARX();                                                                     \
        LGKM0();                                                                    \
        __builtin_amdgcn_sched_barrier(0);                                          \
        __builtin_amdgcn_s_setprio(1);                                              \
        _Pragma("unroll") for (int mi = 0; mi < 4; mi++)                            \
            _Pragma("unroll") for (int nn = 0; nn < 4; nn++)                        \
                acc[mi][nn] = __builtin_amdgcn_mfma_f32_16x16x32_bf16(              \
                    af[mi], bfr[nn], acc[mi][nn], 0, 0, 0);                         \
        __builtin_amdgcn_s_setprio(0);                                              \
        BARX();                                                                     \
    }

#define PHASE_B(BUF, KK, STAGES)                                                    \
    {                                                                               \
        bf16x8 af[4];                                                               \
        lds_char* aB_ = (lds_char*)&As[BUF][1][0];                                  \
        const int co_ = ((KK) * 64 + lg * 16) ^ sw;                                 \
        _Pragma("unroll") for (int mi = 0; mi < 4; mi++)                            \
            af[mi] = dsr128(aB_ + (wm * 64 + mi * 16 + lr) * 128 + co_);            \
        STAGES;                                                                     \
        BARX();                                                                     \
        LGKM0();                                                                    \
        __builtin_amdgcn_sched_barrier(0);                                          \
        __builtin_amdgcn_s_setprio(1);                                              \
        _Pragma("unroll") for (int mi = 0; mi < 4; mi++)                            \
            _Pragma("unroll") for (int nn = 0; nn < 4; nn++)                        \
                acc[4 + mi][nn] = __builtin_amdgcn_mfma_f32_16x16x32_bf16(          \
                    af[mi], bfr[nn], acc[4 + mi][nn], 0, 0, 0);                     \
        __builtin_amdgcn_s_setprio(0);                                              \
        BARX();                                                                     \
    }

    // prologue: buf0 all 4 subs (kt0) + buf1.Asub0 (kt1); drain buf0, keep A10 in flight
    STAGE_A(0, 0, 0); STAGE_A(0, 1, 0); STAGE_B(0, 0, 0); STAGE_B(0, 1, 0);
    STAGE_A(1, 0, 1);
    VMC2();
    BARX();

    for (int it = 0; it < NIT; it++) {
        const int ko  = 2 * it + 1;                 // buf1 data consumed this iter
        const int ke2 = min(2 * it + 2, NKT - 1);   // buf0 next (tail: dead re-stage)
        const int ko2 = min(2 * it + 3, NKT - 1);   // buf1 next
        PHASE_A(0, 0, { STAGE_B(1, 0, ko); STAGE_B(1, 1, ko); });
        PHASE_B(0, 0, { STAGE_A(1, 1, ko); });
        PHASE_A(0, 1, {});
        PHASE_B(0, 1, { STAGE_A(0, 0, ke2); VMC2(); });
        PHASE_A(1, 0, { STAGE_B(0, 0, ke2); STAGE_B(0, 1, ke2); });
        PHASE_B(1, 0, { STAGE_A(0, 1, ke2); });
        PHASE_A(1, 1, {});
        PHASE_B(1, 1, { STAGE_A(1, 0, ko2); VMC2(); });
    }
    VMC0();

#undef PHASE_A
#undef PHASE_B
#undef STAGE_A
#undef STAGE_B

    // epilogue
#pragma unroll
    for (int mq = 0; mq < 2; mq++)
#pragma unroll
        for (int mi = 0; mi < 4; mi++)
#pragma unroll
            for (int nn = 0; nn < 4; nn++) {
                const int row = m0 + wm * 128 + mq * 64 + mi * 16 + lg * 4;
                const int col = n0 + wn * 64 + (nn >> 1) * 32 + (nn & 1) * 16 + lr;
                const float sc = (col < scale_cols) ? scale : 1.0f;
                const f32x4 v = acc[mq * 4 + mi][nn];
#pragma unroll
                for (int j = 0; j < 4; j++) {
                    if (OUT_BF16)
                        ((ushort_t*)C)[(size_t)(row + j) * N + col] = f2b(v[j] * sc);
                    else
                        ((float*)C)[(size_t)(row + j) * N + col] = v[j] * sc;
                }
            }
}

// ------------- flash attention v3: 8 waves x 16 q-rows, paired q-tiles, dbuf gload_lds -------------
__global__ __launch_bounds__(512, 1) void attn_fwd3(const ushort_t* __restrict__ qkvb,
                                                    const ushort_t* __restrict__ vT,
                                                    ushort_t* __restrict__ attnb) {
    __shared__ __align__(16) ushort_t Ks[2][64 * 128];
    __shared__ __align__(16) ushort_t Vs[2][128 * 64];
    __shared__ __align__(16) ushort_t Ps[8][16 * 64];

    const int t = threadIdx.x;
    const int l = t & 63, w = t >> 6;
    const int lr = l & 15, lg = l >> 4;
    const int pr = blockIdx.x, h = blockIdx.y, b = blockIdx.z;

    const ushort_t* kg = qkvb + (size_t)(b * SEQ) * QKVN + HID + h * HD;
    const ushort_t* vg = vT + (size_t)(b * NH + h) * HD * SEQ;

    char* PsB = (char*)Ps[w];
    const int pssz = ((lr & 7) ^ ((lr >> 3) << 1)) << 4;

    const int kcA = 2 * w, kcB = 2 * w + 1;
    const int krA = 8 * w + (l >> 4), krB = krA + 4;
    const int kcolA = ((l & 15) ^ (l >> 4)) << 3;
    const int kcolB = ((l & 15) ^ (4 + (l >> 4))) << 3;
    const int vrA = 16 * w + (l >> 3), vrB = vrA + 8;
    const int vcol = ((l & 7) ^ (l >> 3)) << 3;

    for (int seg = 0; seg < 2; seg++) {
        const int qt = (seg == 0) ? pr : 15 - pr;
        const int q0 = qt * QB;
        const int q0w = q0 + w * 16;
        const int NT = (q0 + QB) / KVB;

        bf16x8 qf[4];
        {
            const ushort_t* qb = qkvb + (size_t)(b * SEQ + q0w + lr) * QKVN + h * HD + lg * 8;
#pragma unroll
            for (int kc = 0; kc < 4; kc++) qf[kc] = *(const bf16x8*)(qb + kc * 32);
        }
        f32x4 o[8] = {};
        float m[4] = {-3e38f, -3e38f, -3e38f, -3e38f};
        float ls[4] = {0.f, 0.f, 0.f, 0.f};

        __syncthreads();
        gload_lds16(kg + (size_t)krA * QKVN + kcolA, &Ks[0][kcA * 512 + l * 8]);
        gload_lds16(kg + (size_t)krB * QKVN + kcolB, &Ks[0][kcB * 512 + l * 8]);
        gload_lds16(vg + (size_t)vrA * SEQ + vcol,   &Vs[0][kcA * 512 + l * 8]);
        gload_lds16(vg + (size_t)vrB * SEQ + vcol,   &Vs[0][kcB * 512 + l * 8]);

        for (int kt = 0; kt < NT; kt++) {
            const int kv0 = kt * KVB;
            __syncthreads();
            if (kt + 1 < NT) {
                const int nb = (kt + 1) & 1;
                const int nkv = kv0 + KVB;
                gload_lds16(kg + (size_t)(nkv + krA) * QKVN + kcolA, &Ks[nb][kcA * 512 + l * 8]);
                gload_lds16(kg + (size_t)(nkv + krB) * QKVN + kcolB, &Ks[nb][kcB * 512 + l * 8]);
                gload_lds16(vg + (size_t)vrA * SEQ + nkv + vcol,     &Vs[nb][kcA * 512 + l * 8]);
                gload_lds16(vg + (size_t)vrB * SEQ + nkv + vcol,     &Vs[nb][kcB * 512 + l * 8]);
            }
            if (kv0 > q0w + 15) continue;
            const char* KsB = (const char*)Ks[kt & 1];
            const char* VsB = (const char*)Vs[kt & 1];

            f32x4 s[4];
            const int rs = (lr & 7) << 4;
#pragma unroll
            for (int nf = 0; nf < 4; nf++) {
                const int r = nf * 16 + lr;
                s[nf] = (f32x4){0.f, 0.f, 0.f, 0.f};
#pragma unroll
                for (int kc = 0; kc < 4; kc++) {
                    bf16x8 kf = *(const bf16x8*)(KsB + r * 256 + ((kc * 64 + lg * 16) ^ rs));
                    s[nf] = __builtin_amdgcn_mfma_f32_16x16x32_bf16(qf[kc], kf, s[nf], 0, 0, 0);
                }
            }

            const bool diag = (kv0 + 63 > q0w);
            float tm[4];
#pragma unroll
            for (int j = 0; j < 4; j++) {
                if (diag) {
                    const int qpos = q0w + lg * 4 + j;
#pragma unroll
                    for (int nf = 0; nf < 4; nf++)
                        if (kv0 + nf * 16 + lr > qpos) s[nf][j] = -3e38f;
                }
                tm[j] = fmaxf(fmaxf(s[0][j], s[1][j]), fmaxf(s[2][j], s[3][j]));
#pragma unroll
                for (int mk = 1; mk < 16; mk <<= 1)
                    tm[j] = fmaxf(tm[j], __shfl_xor(tm[j], mk, 64));
            }

            float grow = fmaxf(fmaxf(tm[0] - m[0], tm[1] - m[1]),
                               fmaxf(tm[2] - m[2], tm[3] - m[3]));
            if (!__all(grow <= 8.0f)) {
#pragma unroll
                for (int j = 0; j < 4; j++) {
                    const float mn = fmaxf(m[j], tm[j]);
                    const float fac = exp2f((m[j] - mn) * 1.44269504f);
                    m[j] = mn; ls[j] *= fac;
#pragma unroll
                    for (int nf2 = 0; nf2 < 8; nf2++) o[nf2][j] *= fac;
                }
            }

#pragma unroll
            for (int j = 0; j < 4; j++) {
                const int row = lg * 4 + j;
                const int rsz = ((row & 7) ^ ((row >> 3) << 1)) << 4;
                float psum = 0.f;
#pragma unroll
                for (int nf = 0; nf < 4; nf++) {
                    float p = exp2f((s[nf][j] - m[j]) * 1.44269504f);
                    psum += p;
                    union { float f; unsigned u; } cv; cv.f = p;
                    *(ushort_t*)(PsB + row * 128 + ((nf * 32 + lr * 2) ^ rsz)) = (ushort_t)(cv.u >> 16);
                }
                ls[j] += psum;
            }

            bf16x8 pa0 = *(const bf16x8*)(PsB + lr * 128 + ((lg * 16) ^ pssz));
            bf16x8 pa1 = *(const bf16x8*)(PsB + lr * 128 + ((64 + lg * 16) ^ pssz));
#pragma unroll
            for (int nf2 = 0; nf2 < 8; nf2++) {
                const int vr2 = nf2 * 16 + lr;
                bf16x8 vb0 = *(const bf16x8*)(VsB + vr2 * 128 + ((lg * 16) ^ rs));
                bf16x8 vb1 = *(const bf16x8*)(VsB + vr2 * 128 + ((64 + lg * 16) ^ rs));
                o[nf2] = __builtin_amdgcn_mfma_f32_16x16x32_bf16(pa0, vb0, o[nf2], 0, 0, 0);
                o[nf2] = __builtin_amdgcn_mfma_f32_16x16x32_bf16(pa1, vb1, o[nf2], 0, 0, 0);
            }
        }

        float inv[4];
#pragma unroll
        for (int j = 0; j < 4; j++) {
            float sum = ls[j];
#pragma unroll
            for (int mk = 1; mk < 16; mk <<= 1) sum += __shfl_xor(sum, mk, 64);
            inv[j] = 1.0f / sum;
        }
        ushort_t* ob = attnb + (size_t)(b * SEQ + q0w) * HID + h * HD;
#pragma unroll
        for (int nf2 = 0; nf2 < 8; nf2++)
#pragma unroll
            for (int j = 0; j < 4; j++)
                ob[(size_t)(lg * 4 + j) * HID + nf2 * 16 + lr] = f2b(o[nf2][j] * inv[j]);
    }
}

extern "C" void kernel_launch(void* const* d_in, const int* in_sizes, int n_in,
                              void* d_out, int out_size, void* d_ws, size_t ws_size,
                              hipStream_t stream) {
    const float* x     = (const float*)d_in[0];
    const float* w_qkv = (const float*)d_in[1];
    const float* w_out = (const float*)d_in[2];
    float* out = (float*)d_out;

    char* ws = (char*)d_ws;
    ushort_t* xb    = (ushort_t*)(ws);                 // 4096x2048 bf16
    ushort_t* wqkvT = (ushort_t*)(ws + 16777216);      // 6144x2048 bf16
    ushort_t* woutT = (ushort_t*)(ws + 41943040);      // 2048x2048 bf16
    ushort_t* qkvb  = (ushort_t*)(ws + 50331648);      // 4096x6144 bf16
    ushort_t* vT    = (ushort_t*)(ws + 100663296);     // [b][h][d][s] bf16
    ushort_t* attnb = (ushort_t*)(ws + 117440512);     // 4096x2048 bf16

    const int M = 2 * SEQ;  // 4096

    castbf<<<(M * HID) / (256 * 8), 256, 0, stream>>>(x, xb, M * HID);
    transcast<<<dim3(QKVN / 32, HID / 32), 256, 0, stream>>>(w_qkv, wqkvT, HID, QKVN);
    transcast<<<dim3(HID / 32, HID / 32), 256, 0, stream>>>(w_out, woutT, HID, HID);

    // qkv = x @ w_qkv, Q pre-scaled by 1/sqrt(HD); 8-phase 256^2 GEMM (asm ds_read)
    gemm8p<true><<<(M / 256) * (QKVN / 256), 512, 0, stream>>>(
        xb, wqkvT, qkvb, M, QKVN, HID, HID, 0.08838834764831845f);

    transV<<<dim3(SEQ / 32, HD / 32, 2 * NH), 256, 0, stream>>>(qkvb, vT);

    attn_fwd3<<<dim3(8, NH, 2), 512, 0, stream>>>(qkvb, vT, attnb);

    gemm8p<false><<<(M / 256) * (HID / 256), 512, 0, stream>>>(
        attnb, woutT, out, M, HID, HID, 0, 1.0f);
}

// Round 8
// 282.887 us; speedup vs baseline: 1.1813x; 1.0202x over previous
//
#include <hip/hip_runtime.h>
#include <hip/hip_bf16.h>

typedef __attribute__((ext_vector_type(8))) short bf16x8;
typedef __attribute__((ext_vector_type(4))) float f32x4;
typedef unsigned short ushort_t;

#define HID 2048
#define QKVN 6144
#define SEQ 2048
#define NH 16
#define HD 128
#define QB 128
#define KVB 64

#define GLOBAL_AS __attribute__((address_space(1)))
#define LDS_AS __attribute__((address_space(3)))
typedef LDS_AS const char lds_char;

__device__ __forceinline__ void gload_lds16(const ushort_t* g, ushort_t* l) {
    __builtin_amdgcn_global_load_lds((const GLOBAL_AS unsigned int*)g,
                                     (LDS_AS unsigned int*)l, 16, 0, 0);
}

// inline-asm ds_read_b128: opaque to SIInsertWaitcnts' LDS-DMA alias check (r7 win).
__device__ __forceinline__ bf16x8 dsr128(lds_char* p) {
    bf16x8 r;
    asm volatile("ds_read_b128 %0, %1" : "=v"(r) : "v"(p));
    return r;
}

__device__ __forceinline__ ushort_t f2b(float f) {
    union { float f; unsigned int u; } x; x.f = f;
    unsigned int r = x.u + 0x7fffu + ((x.u >> 16) & 1u);  // RNE
    return (ushort_t)(r >> 16);
}

#define BARX() asm volatile("s_barrier" ::: "memory")
#define LGKM0() asm volatile("s_waitcnt lgkmcnt(0)" ::: "memory")
#define VMC6() asm volatile("s_waitcnt vmcnt(6)" ::: "memory")
#define VMC0() asm volatile("s_waitcnt vmcnt(0)" ::: "memory")

// ---------------- cast fp32 -> bf16 (vectorized) ----------------
__global__ __launch_bounds__(256) void castbf(const float* __restrict__ in,
                                              ushort_t* __restrict__ out, int n) {
    int i = (blockIdx.x * 256 + threadIdx.x) * 8;
    if (i >= n) return;
    float4 a = *(const float4*)(in + i);
    float4 b = *(const float4*)(in + i + 4);
    union { ushort_t u[8]; uint4 v; } r;
    r.u[0] = f2b(a.x); r.u[1] = f2b(a.y); r.u[2] = f2b(a.z); r.u[3] = f2b(a.w);
    r.u[4] = f2b(b.x); r.u[5] = f2b(b.y); r.u[6] = f2b(b.z); r.u[7] = f2b(b.w);
    *(uint4*)(out + i) = r.v;
}

// ------------- transpose + cast: fp32 K x N  ->  bf16 N x K -------------
__global__ __launch_bounds__(256) void transcast(const float* __restrict__ in,
                                                 ushort_t* __restrict__ out,
                                                 int Kd, int Nd) {
    __shared__ float tile[32][33];
    int tx = threadIdx.x & 31, ty = threadIdx.x >> 5;
    int n0 = blockIdx.x * 32, k0 = blockIdx.y * 32;
    for (int j = 0; j < 4; j++)
        tile[ty + 8 * j][tx] = in[(size_t)(k0 + ty + 8 * j) * Nd + n0 + tx];
    __syncthreads();
    for (int j = 0; j < 4; j++)
        out[(size_t)(n0 + ty + 8 * j) * Kd + k0 + tx] = f2b(tile[tx][ty + 8 * j]);
}

// ------------- transpose V region of qkv (bf16) -> vT[b][h][d][s] -------------
__global__ __launch_bounds__(256) void transV(const ushort_t* __restrict__ qkvb,
                                              ushort_t* __restrict__ vT) {
    __shared__ ushort_t tile[32][33];
    int tx = threadIdx.x & 31, ty = threadIdx.x >> 5;
    int s0 = blockIdx.x * 32, d0 = blockIdx.y * 32;
    int bh = blockIdx.z; int b = bh >> 4, h = bh & 15;
    for (int j = 0; j < 4; j++)
        tile[ty + 8 * j][tx] =
            qkvb[(size_t)(b * SEQ + s0 + ty + 8 * j) * QKVN + 2 * HID + h * HD + d0 + tx];
    __syncthreads();
    for (int j = 0; j < 4; j++)
        vT[((size_t)bh * HD + d0 + ty + 8 * j) * SEQ + s0 + tx] = tile[tx][ty + 8 * j];
}

// ------------- GEMM 128x256, 4-phase/iter, K-split subs, counted vmcnt(6) -------------
// C(MxN) = A(MxK,bf16) * BT(NxK,bf16)^T. BK=64; subs per buffer: {A.k0,A.k1,B.k0,B.k1}.
// Phase(buf,kk): 8 asm ds_read (A.kk rows wm*64.., B.kk rows wn*64..) + 3 gload_lds
// (slot freed previous phase, +2 K-tiles ahead) + vmcnt(6) + barrier + 16 MFMA + barrier.
// Every stage lands 3 phases after issue; vmcnt(6) always drains exactly those.
// Grid: (M/128)*(N/256) — qkv 768 (3 full CU rounds), outproj 256 (1 round).
template <bool OUT_BF16>
__global__ __launch_bounds__(512, 1) void gemm4p(const ushort_t* __restrict__ A,
                                                 const ushort_t* __restrict__ BT,
                                                 void* __restrict__ C,
                                                 int M, int N, int K,
                                                 int scale_cols, float scale) {
    __shared__ __align__(16) ushort_t As[2][2][128 * 32];  // 32 KB
    __shared__ __align__(16) ushort_t Bs[2][2][256 * 32];  // 64 KB

    const int t = threadIdx.x;
    const int l = t & 63, w = t >> 6;
    const int wm = w >> 2, wn = w & 3;          // 2 x 4 waves, wave tile 64x64
    const int lr = l & 15, lg = l >> 4;

    // XCD-aware bijective swizzle (grid % 8 == 0 for all our shapes)
    const int nwg = gridDim.x;
    const int cpx = nwg >> 3;
    const int swb = (blockIdx.x & 7) * cpx + (blockIdx.x >> 3);
    const int NTN = N >> 8;
    const int m0 = (swb / NTN) << 7, n0 = (swb % NTN) << 8;

    const int NKT = K >> 6;
    const int NIT = NKT >> 1;

    f32x4 acc[4][4] = {};

#define STAGE_A(BUF, KK, KT)                                                    \
    do {                                                                        \
        const int r_ = t >> 2, g_ = t & 3;                                      \
        const int gc_ = ((KT) << 6) + ((KK) << 5) + ((g_ ^ (r_ & 3)) << 3);     \
        gload_lds16(A + (size_t)(m0 + r_) * K + gc_, &As[BUF][KK][t * 8]);      \
    } while (0)
#define STAGE_B(BUF, KK, KT)                                                        \
    do {                                                                            \
        _Pragma("unroll") for (int sx = 0; sx < 2; sx++) {                          \
            const int i_ = sx * 512 + t;                                            \
            const int r_ = i_ >> 2, g_ = i_ & 3;                                    \
            const int gc_ = ((KT) << 6) + ((KK) << 5) + ((g_ ^ (r_ & 3)) << 3);     \
            gload_lds16(BT + (size_t)(n0 + r_) * K + gc_, &Bs[BUF][KK][i_ * 8]);    \
        }                                                                           \
    } while (0)

#define PHASE(BUF, KK, STAGES)                                                  \
    {                                                                           \
        bf16x8 af[4], bfr[4];                                                   \
        lds_char* aB_ = (lds_char*)&As[BUF][KK][0];                             \
        lds_char* bB_ = (lds_char*)&Bs[BUF][KK][0];                             \
        const int co_ = (lg ^ (lr & 3)) << 4;                                   \
        _Pragma("unroll") for (int mi = 0; mi < 4; mi++)                        \
            af[mi] = dsr128(aB_ + (wm * 64 + mi * 16 + lr) * 64 + co_);         \
        _Pragma("unroll") for (int nn = 0; nn < 4; nn++)                        \
            bfr[nn] = dsr128(bB_ + (wn * 64 + nn * 16 + lr) * 64 + co_);        \
        STAGES;                                                                 \
        VMC6();                                                                 \
        BARX();                                                                 \
        LGKM0();                                                                \
        __builtin_amdgcn_sched_barrier(0);                                      \
        __builtin_amdgcn_s_setprio(1);                                          \
        _Pragma("unroll") for (int mi = 0; mi < 4; mi++)                        \
            _Pragma("unroll") for (int nn = 0; nn < 4; nn++)                    \
                acc[mi][nn] = __builtin_amdgcn_mfma_f32_16x16x32_bf16(          \
                    af[mi], bfr[nn], acc[mi][nn], 0, 0, 0);                     \
        __builtin_amdgcn_s_setprio(0);                                          \
        BARX();                                                                 \
    }

    // prologue: t0.k0, t0.k1, t1.k0 (9 loads); vmcnt(6) drains t0.k0; barrier
    STAGE_A(0, 0, 0); STAGE_B(0, 0, 0);
    STAGE_A(0, 1, 0); STAGE_B(0, 1, 0);
    STAGE_A(1, 0, 1); STAGE_B(1, 0, 1);
    VMC6();
    BARX();

    for (int it = 0; it < NIT; it++) {
        const int kt1 = 2 * it + 1;
        const int kt2 = min(2 * it + 2, NKT - 1);   // tail: dead re-stage (no future reader)
        const int kt3 = min(2 * it + 3, NKT - 1);
        PHASE(0, 0, { STAGE_A(1, 1, kt1); STAGE_B(1, 1, kt1); });
        PHASE(0, 1, { STAGE_A(0, 0, kt2); STAGE_B(0, 0, kt2); });
        PHASE(1, 0, { STAGE_A(0, 1, kt2); STAGE_B(0, 1, kt2); });
        PHASE(1, 1, { STAGE_A(1, 0, kt3); STAGE_B(1, 0, kt3); });
    }
    VMC0();

#undef PHASE
#undef STAGE_A
#undef STAGE_B

    // epilogue
#pragma unroll
    for (int mi = 0; mi < 4; mi++)
#pragma unroll
        for (int nn = 0; nn < 4; nn++) {
            const int row = m0 + wm * 64 + mi * 16 + lg * 4;
            const int col = n0 + wn * 64 + nn * 16 + lr;
            const float sc = (col < scale_cols) ? scale : 1.0f;
            const f32x4 v = acc[mi][nn];
#pragma unroll
            for (int j = 0; j < 4; j++) {
                if (OUT_BF16)
                    ((ushort_t*)C)[(size_t)(row + j) * N + col] = f2b(v[j] * sc);
                else
                    ((float*)C)[(size_t)(row + j) * N + col] = v[j] * sc;
            }
        }
}

// ------------- flash attention v3: 8 waves x 16 q-rows, paired q-tiles, dbuf gload_lds -------------
__global__ __launch_bounds__(512, 1) void attn_fwd3(const ushort_t* __restrict__ qkvb,
                                                    const ushort_t* __restrict__ vT,
                                                    ushort_t* __restrict__ attnb) {
    __shared__ __align__(16) ushort_t Ks[2][64 * 128];
    __shared__ __align__(16) ushort_t Vs[2][128 * 64];
    __shared__ __align__(16) ushort_t Ps[8][16 * 64];

    const int t = threadIdx.x;
    const int l = t & 63, w = t >> 6;
    const int lr = l & 15, lg = l >> 4;
    const int pr = blockIdx.x, h = blockIdx.y, b = blockIdx.z;

    const ushort_t* kg = qkvb + (size_t)(b * SEQ) * QKVN + HID + h * HD;
    const ushort_t* vg = vT + (size_t)(b * NH + h) * HD * SEQ;

    char* PsB = (char*)Ps[w];
    const int pssz = ((lr & 7) ^ ((lr >> 3) << 1)) << 4;

    const int kcA = 2 * w, kcB = 2 * w + 1;
    const int krA = 8 * w + (l >> 4), krB = krA + 4;
    const int kcolA = ((l & 15) ^ (l >> 4)) << 3;
    const int kcolB = ((l & 15) ^ (4 + (l >> 4))) << 3;
    const int vrA = 16 * w + (l >> 3), vrB = vrA + 8;
    const int vcol = ((l & 7) ^ (l >> 3)) << 3;

    for (int seg = 0; seg < 2; seg++) {
        const int qt = (seg == 0) ? pr : 15 - pr;
        const int q0 = qt * QB;
        const int q0w = q0 + w * 16;
        const int NT = (q0 + QB) / KVB;

        bf16x8 qf[4];
        {
            const ushort_t* qb = qkvb + (size_t)(b * SEQ + q0w + lr) * QKVN + h * HD + lg * 8;
#pragma unroll
            for (int kc = 0; kc < 4; kc++) qf[kc] = *(const bf16x8*)(qb + kc * 32);
        }
        f32x4 o[8] = {};
        float m[4] = {-3e38f, -3e38f, -3e38f, -3e38f};
        float ls[4] = {0.f, 0.f, 0.f, 0.f};

        __syncthreads();
        gload_lds16(kg + (size_t)krA * QKVN + kcolA, &Ks[0][kcA * 512 + l * 8]);
        gload_lds16(kg + (size_t)krB * QKVN + kcolB, &Ks[0][kcB * 512 + l * 8]);
        gload_lds16(vg + (size_t)vrA * SEQ + vcol,   &Vs[0][kcA * 512 + l * 8]);
        gload_lds16(vg + (size_t)vrB * SEQ + vcol,   &Vs[0][kcB * 512 + l * 8]);

        for (int kt = 0; kt < NT; kt++) {
            const int kv0 = kt * KVB;
            __syncthreads();
            if (kt + 1 < NT) {
                const int nb = (kt + 1) & 1;
                const int nkv = kv0 + KVB;
                gload_lds16(kg + (size_t)(nkv + krA) * QKVN + kcolA, &Ks[nb][kcA * 512 + l * 8]);
                gload_lds16(kg + (size_t)(nkv + krB) * QKVN + kcolB, &Ks[nb][kcB * 512 + l * 8]);
                gload_lds16(vg + (size_t)vrA * SEQ + nkv + vcol,     &Vs[nb][kcA * 512 + l * 8]);
                gload_lds16(vg + (size_t)vrB * SEQ + nkv + vcol,     &Vs[nb][kcB * 512 + l * 8]);
            }
            if (kv0 > q0w + 15) continue;
            const char* KsB = (const char*)Ks[kt & 1];
            const char* VsB = (const char*)Vs[kt & 1];

            f32x4 s[4];
            const int rs = (lr & 7) << 4;
#pragma unroll
            for (int nf = 0; nf < 4; nf++) {
                const int r = nf * 16 + lr;
                s[nf] = (f32x4){0.f, 0.f, 0.f, 0.f};
#pragma unroll
                for (int kc = 0; kc < 4; kc++) {
                    bf16x8 kf = *(const bf16x8*)(KsB + r * 256 + ((kc * 64 + lg * 16) ^ rs));
                    s[nf] = __builtin_amdgcn_mfma_f32_16x16x32_bf16(qf[kc], kf, s[nf], 0, 0, 0);
                }
            }

            const bool diag = (kv0 + 63 > q0w);
            float tm[4];
#pragma unroll
            for (int j = 0; j < 4; j++) {
                if (diag) {
                    const int qpos = q0w + lg * 4 + j;
#pragma unroll
                    for (int nf = 0; nf < 4; nf++)
                        if (kv0 + nf * 16 + lr > qpos) s[nf][j] = -3e38f;
                }
                tm[j] = fmaxf(fmaxf(s[0][j], s[1][j]), fmaxf(s[2][j], s[3][j]));
#pragma unroll
                for (int mk = 1; mk < 16; mk <<= 1)
                    tm[j] = fmaxf(tm[j], __shfl_xor(tm[j], mk, 64));
            }

            float grow = fmaxf(fmaxf(tm[0] - m[0], tm[1] - m[1]),
                               fmaxf(tm[2] - m[2], tm[3] - m[3]));
            if (!__all(grow <= 8.0f)) {
#pragma unroll
                for (int j = 0; j < 4; j++) {
                    const float mn = fmaxf(m[j], tm[j]);
                    const float fac = exp2f((m[j] - mn) * 1.44269504f);
                    m[j] = mn; ls[j] *= fac;
#pragma unroll
                    for (int nf2 = 0; nf2 < 8; nf2++) o[nf2][j] *= fac;
                }
            }

#pragma unroll
            for (int j = 0; j < 4; j++) {
                const int row = lg * 4 + j;
                const int rsz = ((row & 7) ^ ((row >> 3) << 1)) << 4;
                float psum = 0.f;
#pragma unroll
                for (int nf = 0; nf < 4; nf++) {
                    float p = exp2f((s[nf][j] - m[j]) * 1.44269504f);
                    psum += p;
                    union { float f; unsigned u; } cv; cv.f = p;
                    *(ushort_t*)(PsB + row * 128 + ((nf * 32 + lr * 2) ^ rsz)) = (ushort_t)(cv.u >> 16);
                }
                ls[j] += psum;
            }

            bf16x8 pa0 = *(const bf16x8*)(PsB + lr * 128 + ((lg * 16) ^ pssz));
            bf16x8 pa1 = *(const bf16x8*)(PsB + lr * 128 + ((64 + lg * 16) ^ pssz));
#pragma unroll
            for (int nf2 = 0; nf2 < 8; nf2++) {
                const int vr2 = nf2 * 16 + lr;
                bf16x8 vb0 = *(const bf16x8*)(VsB + vr2 * 128 + ((lg * 16) ^ rs));
                bf16x8 vb1 = *(const bf16x8*)(VsB + vr2 * 128 + ((64 + lg * 16) ^ rs));
                o[nf2] = __builtin_amdgcn_mfma_f32_16x16x32_bf16(pa0, vb0, o[nf2], 0, 0, 0);
                o[nf2] = __builtin_amdgcn_mfma_f32_16x16x32_bf16(pa1, vb1, o[nf2], 0, 0, 0);
            }
        }

        float inv[4];
#pragma unroll
        for (int j = 0; j < 4; j++) {
            float sum = ls[j];
#pragma unroll
            for (int mk = 1; mk < 16; mk <<= 1) sum += __shfl_xor(sum, mk, 64);
            inv[j] = 1.0f / sum;
        }
        ushort_t* ob = attnb + (size_t)(b * SEQ + q0w) * HID + h * HD;
#pragma unroll
        for (int nf2 = 0; nf2 < 8; nf2++)
#pragma unroll
            for (int j = 0; j < 4; j++)
                ob[(size_t)(lg * 4 + j) * HID + nf2 * 16 + lr] = f2b(o[nf2][j] * inv[j]);
    }
}

extern "C" void kernel_launch(void* const* d_in, const int* in_sizes, int n_in,
                              void* d_out, int out_size, void* d_ws, size_t ws_size,
                              hipStream_t stream) {
    const float* x     = (const float*)d_in[0];
    const float* w_qkv = (const float*)d_in[1];
    const float* w_out = (const float*)d_in[2];
    float* out = (float*)d_out;

    char* ws = (char*)d_ws;
    ushort_t* xb    = (ushort_t*)(ws);                 // 4096x2048 bf16
    ushort_t* wqkvT = (ushort_t*)(ws + 16777216);      // 6144x2048 bf16
    ushort_t* woutT = (ushort_t*)(ws + 41943040);      // 2048x2048 bf16
    ushort_t* qkvb  = (ushort_t*)(ws + 50331648);      // 4096x6144 bf16
    ushort_t* vT    = (ushort_t*)(ws + 100663296);     // [b][h][d][s] bf16
    ushort_t* attnb = (ushort_t*)(ws + 117440512);     // 4096x2048 bf16

    const int M = 2 * SEQ;  // 4096

    castbf<<<(M * HID) / (256 * 8), 256, 0, stream>>>(x, xb, M * HID);
    transcast<<<dim3(QKVN / 32, HID / 32), 256, 0, stream>>>(w_qkv, wqkvT, HID, QKVN);
    transcast<<<dim3(HID / 32, HID / 32), 256, 0, stream>>>(w_out, woutT, HID, HID);

    // qkv = x @ w_qkv, Q pre-scaled by 1/sqrt(HD); 128x256 4-phase GEMM, 768 blocks
    gemm4p<true><<<(M / 128) * (QKVN / 256), 512, 0, stream>>>(
        xb, wqkvT, qkvb, M, QKVN, HID, HID, 0.08838834764831845f);

    transV<<<dim3(SEQ / 32, HD / 32, 2 * NH), 256, 0, stream>>>(qkvb, vT);

    attn_fwd3<<<dim3(8, NH, 2), 512, 0, stream>>>(qkvb, vT, attnb);

    // out = attn @ w_out; 128x256 4-phase GEMM, 256 blocks (full GPU, 1 round)
    gemm4p<false><<<(M / 128) * (HID / 256), 512, 0, stream>>>(
        attnb, woutT, out, M, HID, HID, 0, 1.0f);
}

// Round 9
// 276.039 us; speedup vs baseline: 1.2106x; 1.0248x over previous
//
#include <hip/hip_runtime.h>
#include <hip/hip_bf16.h>

typedef __attribute__((ext_vector_type(8))) short bf16x8;
typedef __attribute__((ext_vector_type(4))) float f32x4;
typedef unsigned short ushort_t;

#define HID 2048
#define QKVN 6144
#define SEQ 2048
#define NH 16
#define HD 128
#define QB 128
#define KVB 64

#define GLOBAL_AS __attribute__((address_space(1)))
#define LDS_AS __attribute__((address_space(3)))
typedef LDS_AS const char lds_char;

__device__ __forceinline__ void gload_lds16(const ushort_t* g, ushort_t* l) {
    __builtin_amdgcn_global_load_lds((const GLOBAL_AS unsigned int*)g,
                                     (LDS_AS unsigned int*)l, 16, 0, 0);
}

// inline-asm ds_read_b128: opaque to SIInsertWaitcnts' LDS-DMA alias check (r7 win).
__device__ __forceinline__ bf16x8 dsr128(lds_char* p) {
    bf16x8 r;
    asm volatile("ds_read_b128 %0, %1" : "=v"(r) : "v"(p));
    return r;
}

__device__ __forceinline__ ushort_t f2b(float f) {
    union { float f; unsigned int u; } x; x.f = f;
    unsigned int r = x.u + 0x7fffu + ((x.u >> 16) & 1u);  // RNE
    return (ushort_t)(r >> 16);
}

#define BARX() asm volatile("s_barrier" ::: "memory")
#define LGKM0() asm volatile("s_waitcnt lgkmcnt(0)" ::: "memory")
#define VMC6() asm volatile("s_waitcnt vmcnt(6)" ::: "memory")
#define VMC0() asm volatile("s_waitcnt vmcnt(0)" ::: "memory")

// ---------------- cast fp32 -> bf16 (vectorized) ----------------
__global__ __launch_bounds__(256) void castbf(const float* __restrict__ in,
                                              ushort_t* __restrict__ out, int n) {
    int i = (blockIdx.x * 256 + threadIdx.x) * 8;
    if (i >= n) return;
    float4 a = *(const float4*)(in + i);
    float4 b = *(const float4*)(in + i + 4);
    union { ushort_t u[8]; uint4 v; } r;
    r.u[0] = f2b(a.x); r.u[1] = f2b(a.y); r.u[2] = f2b(a.z); r.u[3] = f2b(a.w);
    r.u[4] = f2b(b.x); r.u[5] = f2b(b.y); r.u[6] = f2b(b.z); r.u[7] = f2b(b.w);
    *(uint4*)(out + i) = r.v;
}

// ------------- transpose + cast: fp32 K x N  ->  bf16 N x K -------------
__global__ __launch_bounds__(256) void transcast(const float* __restrict__ in,
                                                 ushort_t* __restrict__ out,
                                                 int Kd, int Nd) {
    __shared__ float tile[32][33];
    int tx = threadIdx.x & 31, ty = threadIdx.x >> 5;
    int n0 = blockIdx.x * 32, k0 = blockIdx.y * 32;
    for (int j = 0; j < 4; j++)
        tile[ty + 8 * j][tx] = in[(size_t)(k0 + ty + 8 * j) * Nd + n0 + tx];
    __syncthreads();
    for (int j = 0; j < 4; j++)
        out[(size_t)(n0 + ty + 8 * j) * Kd + k0 + tx] = f2b(tile[tx][ty + 8 * j]);
}

// ------------- transpose V region of qkv (bf16) -> vT[b][h][d][s] -------------
__global__ __launch_bounds__(256) void transV(const ushort_t* __restrict__ qkvb,
                                              ushort_t* __restrict__ vT) {
    __shared__ ushort_t tile[32][33];
    int tx = threadIdx.x & 31, ty = threadIdx.x >> 5;
    int s0 = blockIdx.x * 32, d0 = blockIdx.y * 32;
    int bh = blockIdx.z; int b = bh >> 4, h = bh & 15;
    for (int j = 0; j < 4; j++)
        tile[ty + 8 * j][tx] =
            qkvb[(size_t)(b * SEQ + s0 + ty + 8 * j) * QKVN + 2 * HID + h * HD + d0 + tx];
    __syncthreads();
    for (int j = 0; j < 4; j++)
        vT[((size_t)bh * HD + d0 + ty + 8 * j) * SEQ + s0 + tx] = tile[tx][ty + 8 * j];
}

// ------------- GEMM 128x256, 4-phase/iter, K-split subs, counted vmcnt(6) -------------
// C(MxN) = A(MxK,bf16) * BT(NxK,bf16)^T. BK=64; subs per buffer: {A.k0,A.k1,B.k0,B.k1}.
// LDS sub rows are 64 B (4 x 16B granules). Swizzle: granule g at row r holds global
// granule g ^ ((r>>1)&3) -> any 8 sequential lanes cover all 8 (row-parity, granule)
// combos = 32 banks, so ds_read_b128 batches are conflict-free (r8 had lg^(lr&3): 2-way).
template <bool OUT_BF16>
__global__ __launch_bounds__(512, 1) void gemm4p(const ushort_t* __restrict__ A,
                                                 const ushort_t* __restrict__ BT,
                                                 void* __restrict__ C,
                                                 int M, int N, int K,
                                                 int scale_cols, float scale) {
    __shared__ __align__(16) ushort_t As[2][2][128 * 32];  // 32 KB
    __shared__ __align__(16) ushort_t Bs[2][2][256 * 32];  // 64 KB

    const int t = threadIdx.x;
    const int l = t & 63, w = t >> 6;
    const int wm = w >> 2, wn = w & 3;          // 2 x 4 waves, wave tile 64x64
    const int lr = l & 15, lg = l >> 4;

    // XCD-aware bijective swizzle (grid % 8 == 0 for all our shapes)
    const int nwg = gridDim.x;
    const int cpx = nwg >> 3;
    const int swb = (blockIdx.x & 7) * cpx + (blockIdx.x >> 3);
    const int NTN = N >> 8;
    const int m0 = (swb / NTN) << 7, n0 = (swb % NTN) << 8;

    const int NKT = K >> 6;
    const int NIT = NKT >> 1;

    f32x4 acc[4][4] = {};

#define STAGE_A(BUF, KK, KT)                                                       \
    do {                                                                           \
        const int r_ = t >> 2, g_ = t & 3;                                         \
        const int gc_ = ((KT) << 6) + ((KK) << 5) + ((g_ ^ ((r_ >> 1) & 3)) << 3); \
        gload_lds16(A + (size_t)(m0 + r_) * K + gc_, &As[BUF][KK][t * 8]);         \
    } while (0)
#define STAGE_B(BUF, KK, KT)                                                           \
    do {                                                                               \
        _Pragma("unroll") for (int sx = 0; sx < 2; sx++) {                             \
            const int i_ = sx * 512 + t;                                               \
            const int r_ = i_ >> 2, g_ = i_ & 3;                                       \
            const int gc_ = ((KT) << 6) + ((KK) << 5) + ((g_ ^ ((r_ >> 1) & 3)) << 3); \
            gload_lds16(BT + (size_t)(n0 + r_) * K + gc_, &Bs[BUF][KK][i_ * 8]);       \
        }                                                                              \
    } while (0)

#define PHASE(BUF, KK, STAGES)                                                  \
    {                                                                           \
        bf16x8 af[4], bfr[4];                                                   \
        lds_char* aB_ = (lds_char*)&As[BUF][KK][0];                             \
        lds_char* bB_ = (lds_char*)&Bs[BUF][KK][0];                             \
        const int co_ = (lg ^ ((lr >> 1) & 3)) << 4;                            \
        _Pragma("unroll") for (int mi = 0; mi < 4; mi++)                        \
            af[mi] = dsr128(aB_ + (wm * 64 + mi * 16 + lr) * 64 + co_);         \
        _Pragma("unroll") for (int nn = 0; nn < 4; nn++)                        \
            bfr[nn] = dsr128(bB_ + (wn * 64 + nn * 16 + lr) * 64 + co_);        \
        STAGES;                                                                 \
        VMC6();                                                                 \
        BARX();                                                                 \
        LGKM0();                                                                \
        __builtin_amdgcn_sched_barrier(0);                                      \
        __builtin_amdgcn_s_setprio(1);                                          \
        _Pragma("unroll") for (int mi = 0; mi < 4; mi++)                        \
            _Pragma("unroll") for (int nn = 0; nn < 4; nn++)                    \
                acc[mi][nn] = __builtin_amdgcn_mfma_f32_16x16x32_bf16(          \
                    af[mi], bfr[nn], acc[mi][nn], 0, 0, 0);                     \
        __builtin_amdgcn_s_setprio(0);                                          \
        BARX();                                                                 \
    }

    // prologue: t0.k0, t0.k1, t1.k0 (9 loads); vmcnt(6) drains t0.k0; barrier
    STAGE_A(0, 0, 0); STAGE_B(0, 0, 0);
    STAGE_A(0, 1, 0); STAGE_B(0, 1, 0);
    STAGE_A(1, 0, 1); STAGE_B(1, 0, 1);
    VMC6();
    BARX();

    for (int it = 0; it < NIT; it++) {
        const int kt1 = 2 * it + 1;
        const int kt2 = min(2 * it + 2, NKT - 1);   // tail: dead re-stage (no future reader)
        const int kt3 = min(2 * it + 3, NKT - 1);
        PHASE(0, 0, { STAGE_A(1, 1, kt1); STAGE_B(1, 1, kt1); });
        PHASE(0, 1, { STAGE_A(0, 0, kt2); STAGE_B(0, 0, kt2); });
        PHASE(1, 0, { STAGE_A(0, 1, kt2); STAGE_B(0, 1, kt2); });
        PHASE(1, 1, { STAGE_A(1, 0, kt3); STAGE_B(1, 0, kt3); });
    }
    VMC0();

#undef PHASE
#undef STAGE_A
#undef STAGE_B

    // epilogue
#pragma unroll
    for (int mi = 0; mi < 4; mi++)
#pragma unroll
        for (int nn = 0; nn < 4; nn++) {
            const int row = m0 + wm * 64 + mi * 16 + lg * 4;
            const int col = n0 + wn * 64 + nn * 16 + lr;
            const float sc = (col < scale_cols) ? scale : 1.0f;
            const f32x4 v = acc[mi][nn];
#pragma unroll
            for (int j = 0; j < 4; j++) {
                if (OUT_BF16)
                    ((ushort_t*)C)[(size_t)(row + j) * N + col] = f2b(v[j] * sc);
                else
                    ((float*)C)[(size_t)(row + j) * N + col] = v[j] * sc;
            }
        }
}

// ------------- flash attention v3: 8 waves x 16 q-rows, paired q-tiles, dbuf gload_lds -------------
__global__ __launch_bounds__(512, 1) void attn_fwd3(const ushort_t* __restrict__ qkvb,
                                                    const ushort_t* __restrict__ vT,
                                                    ushort_t* __restrict__ attnb) {
    __shared__ __align__(16) ushort_t Ks[2][64 * 128];
    __shared__ __align__(16) ushort_t Vs[2][128 * 64];
    __shared__ __align__(16) ushort_t Ps[8][16 * 64];

    const int t = threadIdx.x;
    const int l = t & 63, w = t >> 6;
    const int lr = l & 15, lg = l >> 4;
    const int pr = blockIdx.x, h = blockIdx.y, b = blockIdx.z;

    const ushort_t* kg = qkvb + (size_t)(b * SEQ) * QKVN + HID + h * HD;
    const ushort_t* vg = vT + (size_t)(b * NH + h) * HD * SEQ;

    char* PsB = (char*)Ps[w];
    const int pssz = ((lr & 7) ^ ((lr >> 3) << 1)) << 4;

    const int kcA = 2 * w, kcB = 2 * w + 1;
    const int krA = 8 * w + (l >> 4), krB = krA + 4;
    const int kcolA = ((l & 15) ^ (l >> 4)) << 3;
    const int kcolB = ((l & 15) ^ (4 + (l >> 4))) << 3;
    const int vrA = 16 * w + (l >> 3), vrB = vrA + 8;
    const int vcol = ((l & 7) ^ (l >> 3)) << 3;

    for (int seg = 0; seg < 2; seg++) {
        const int qt = (seg == 0) ? pr : 15 - pr;
        const int q0 = qt * QB;
        const int q0w = q0 + w * 16;
        const int NT = (q0 + QB) / KVB;

        bf16x8 qf[4];
        {
            const ushort_t* qb = qkvb + (size_t)(b * SEQ + q0w + lr) * QKVN + h * HD + lg * 8;
#pragma unroll
            for (int kc = 0; kc < 4; kc++) qf[kc] = *(const bf16x8*)(qb + kc * 32);
        }
        f32x4 o[8] = {};
        float m[4] = {-3e38f, -3e38f, -3e38f, -3e38f};
        float ls[4] = {0.f, 0.f, 0.f, 0.f};

        __syncthreads();
        gload_lds16(kg + (size_t)krA * QKVN + kcolA, &Ks[0][kcA * 512 + l * 8]);
        gload_lds16(kg + (size_t)krB * QKVN + kcolB, &Ks[0][kcB * 512 + l * 8]);
        gload_lds16(vg + (size_t)vrA * SEQ + vcol,   &Vs[0][kcA * 512 + l * 8]);
        gload_lds16(vg + (size_t)vrB * SEQ + vcol,   &Vs[0][kcB * 512 + l * 8]);

        for (int kt = 0; kt < NT; kt++) {
            const int kv0 = kt * KVB;
            __syncthreads();
            if (kt + 1 < NT) {
                const int nb = (kt + 1) & 1;
                const int nkv = kv0 + KVB;
                gload_lds16(kg + (size_t)(nkv + krA) * QKVN + kcolA, &Ks[nb][kcA * 512 + l * 8]);
                gload_lds16(kg + (size_t)(nkv + krB) * QKVN + kcolB, &Ks[nb][kcB * 512 + l * 8]);
                gload_lds16(vg + (size_t)vrA * SEQ + nkv + vcol,     &Vs[nb][kcA * 512 + l * 8]);
                gload_lds16(vg + (size_t)vrB * SEQ + nkv + vcol,     &Vs[nb][kcB * 512 + l * 8]);
            }
            if (kv0 > q0w + 15) continue;
            const char* KsB = (const char*)Ks[kt & 1];
            const char* VsB = (const char*)Vs[kt & 1];

            f32x4 s[4];
            const int rs = (lr & 7) << 4;
#pragma unroll
            for (int nf = 0; nf < 4; nf++) {
                const int r = nf * 16 + lr;
                s[nf] = (f32x4){0.f, 0.f, 0.f, 0.f};
#pragma unroll
                for (int kc = 0; kc < 4; kc++) {
                    bf16x8 kf = *(const bf16x8*)(KsB + r * 256 + ((kc * 64 + lg * 16) ^ rs));
                    s[nf] = __builtin_amdgcn_mfma_f32_16x16x32_bf16(qf[kc], kf, s[nf], 0, 0, 0);
                }
            }

            const bool diag = (kv0 + 63 > q0w);
            float tm[4];
#pragma unroll
            for (int j = 0; j < 4; j++) {
                if (diag) {
                    const int qpos = q0w + lg * 4 + j;
#pragma unroll
                    for (int nf = 0; nf < 4; nf++)
                        if (kv0 + nf * 16 + lr > qpos) s[nf][j] = -3e38f;
                }
                tm[j] = fmaxf(fmaxf(s[0][j], s[1][j]), fmaxf(s[2][j], s[3][j]));
#pragma unroll
                for (int mk = 1; mk < 16; mk <<= 1)
                    tm[j] = fmaxf(tm[j], __shfl_xor(tm[j], mk, 64));
            }

            float grow = fmaxf(fmaxf(tm[0] - m[0], tm[1] - m[1]),
                               fmaxf(tm[2] - m[2], tm[3] - m[3]));
            if (!__all(grow <= 8.0f)) {
#pragma unroll
                for (int j = 0; j < 4; j++) {
                    const float mn = fmaxf(m[j], tm[j]);
                    const float fac = exp2f((m[j] - mn) * 1.44269504f);
                    m[j] = mn; ls[j] *= fac;
#pragma unroll
                    for (int nf2 = 0; nf2 < 8; nf2++) o[nf2][j] *= fac;
                }
            }

#pragma unroll
            for (int j = 0; j < 4; j++) {
                const int row = lg * 4 + j;
                const int rsz = ((row & 7) ^ ((row >> 3) << 1)) << 4;
                float psum = 0.f;
#pragma unroll
                for (int nf = 0; nf < 4; nf++) {
                    float p = exp2f((s[nf][j] - m[j]) * 1.44269504f);
                    psum += p;
                    union { float f; unsigned u; } cv; cv.f = p;
                    *(ushort_t*)(PsB + row * 128 + ((nf * 32 + lr * 2) ^ rsz)) = (ushort_t)(cv.u >> 16);
                }
                ls[j] += psum;
            }

            bf16x8 pa0 = *(const bf16x8*)(PsB + lr * 128 + ((lg * 16) ^ pssz));
            bf16x8 pa1 = *(const bf16x8*)(PsB + lr * 128 + ((64 + lg * 16) ^ pssz));
#pragma unroll
            for (int nf2 = 0; nf2 < 8; nf2++) {
                const int vr2 = nf2 * 16 + lr;
                bf16x8 vb0 = *(const bf16x8*)(VsB + vr2 * 128 + ((lg * 16) ^ rs));
                bf16x8 vb1 = *(const bf16x8*)(VsB + vr2 * 128 + ((64 + lg * 16) ^ rs));
                o[nf2] = __builtin_amdgcn_mfma_f32_16x16x32_bf16(pa0, vb0, o[nf2], 0, 0, 0);
                o[nf2] = __builtin_amdgcn_mfma_f32_16x16x32_bf16(pa1, vb1, o[nf2], 0, 0, 0);
            }
        }

        float inv[4];
#pragma unroll
        for (int j = 0; j < 4; j++) {
            float sum = ls[j];
#pragma unroll
            for (int mk = 1; mk < 16; mk <<= 1) sum += __shfl_xor(sum, mk, 64);
            inv[j] = 1.0f / sum;
        }
        ushort_t* ob = attnb + (size_t)(b * SEQ + q0w) * HID + h * HD;
#pragma unroll
        for (int nf2 = 0; nf2 < 8; nf2++)
#pragma unroll
            for (int j = 0; j < 4; j++)
                ob[(size_t)(lg * 4 + j) * HID + nf2 * 16 + lr] = f2b(o[nf2][j] * inv[j]);
    }
}

extern "C" void kernel_launch(void* const* d_in, const int* in_sizes, int n_in,
                              void* d_out, int out_size, void* d_ws, size_t ws_size,
                              hipStream_t stream) {
    const float* x     = (const float*)d_in[0];
    const float* w_qkv = (const float*)d_in[1];
    const float* w_out = (const float*)d_in[2];
    float* out = (float*)d_out;

    char* ws = (char*)d_ws;
    ushort_t* xb    = (ushort_t*)(ws);                 // 4096x2048 bf16
    ushort_t* wqkvT = (ushort_t*)(ws + 16777216);      // 6144x2048 bf16
    ushort_t* woutT = (ushort_t*)(ws + 41943040);      // 2048x2048 bf16
    ushort_t* qkvb  = (ushort_t*)(ws + 50331648);      // 4096x6144 bf16
    ushort_t* vT    = (ushort_t*)(ws + 100663296);     // [b][h][d][s] bf16
    ushort_t* attnb = (ushort_t*)(ws + 117440512);     // 4096x2048 bf16

    const int M = 2 * SEQ;  // 4096

    castbf<<<(M * HID) / (256 * 8), 256, 0, stream>>>(x, xb, M * HID);
    transcast<<<dim3(QKVN / 32, HID / 32), 256, 0, stream>>>(w_qkv, wqkvT, HID, QKVN);
    transcast<<<dim3(HID / 32, HID / 32), 256, 0, stream>>>(w_out, woutT, HID, HID);

    // qkv = x @ w_qkv, Q pre-scaled by 1/sqrt(HD); 128x256 4-phase GEMM, 768 blocks
    gemm4p<true><<<(M / 128) * (QKVN / 256), 512, 0, stream>>>(
        xb, wqkvT, qkvb, M, QKVN, HID, HID, 0.08838834764831845f);

    transV<<<dim3(SEQ / 32, HD / 32, 2 * NH), 256, 0, stream>>>(qkvb, vT);

    attn_fwd3<<<dim3(8, NH, 2), 512, 0, stream>>>(qkvb, vT, attnb);

    // out = attn @ w_out; 128x256 4-phase GEMM, 256 blocks (full GPU, 1 round)
    gemm4p<false><<<(M / 128) * (HID / 256), 512, 0, stream>>>(
        attnb, woutT, out, M, HID, HID, 0, 1.0f);
}

// Round 10
// 268.424 us; speedup vs baseline: 1.2449x; 1.0284x over previous
//
#include <hip/hip_runtime.h>
#include <hip/hip_bf16.h>

typedef __attribute__((ext_vector_type(8))) short bf16x8;
typedef __attribute__((ext_vector_type(4))) float f32x4;
typedef unsigned short ushort_t;

#define HID 2048
#define QKVN 6144
#define SEQ 2048
#define NH 16
#define HD 128
#define QB 128
#define KVB 64

#define GLOBAL_AS __attribute__((address_space(1)))
#define LDS_AS __attribute__((address_space(3)))
typedef LDS_AS const char lds_char;

__device__ __forceinline__ void gload_lds16(const ushort_t* g, ushort_t* l) {
    __builtin_amdgcn_global_load_lds((const GLOBAL_AS unsigned int*)g,
                                     (LDS_AS unsigned int*)l, 16, 0, 0);
}

// inline-asm ds_read_b128: opaque to SIInsertWaitcnts' LDS-DMA alias check (r7 win).
__device__ __forceinline__ bf16x8 dsr128(lds_char* p) {
    bf16x8 r;
    asm volatile("ds_read_b128 %0, %1" : "=v"(r) : "v"(p));
    return r;
}

__device__ __forceinline__ ushort_t f2b(float f) {
    union { float f; unsigned int u; } x; x.f = f;
    unsigned int r = x.u + 0x7fffu + ((x.u >> 16) & 1u);  // RNE
    return (ushort_t)(r >> 16);
}

#define BARX() asm volatile("s_barrier" ::: "memory")
#define LGKM0() asm volatile("s_waitcnt lgkmcnt(0)" ::: "memory")
#define VMC4() asm volatile("s_waitcnt vmcnt(4)" ::: "memory")
#define VMC6() asm volatile("s_waitcnt vmcnt(6)" ::: "memory")
#define VMC0() asm volatile("s_waitcnt vmcnt(0)" ::: "memory")

// ---------------- cast fp32 -> bf16 (vectorized) ----------------
__global__ __launch_bounds__(256) void castbf(const float* __restrict__ in,
                                              ushort_t* __restrict__ out, int n) {
    int i = (blockIdx.x * 256 + threadIdx.x) * 8;
    if (i >= n) return;
    float4 a = *(const float4*)(in + i);
    float4 b = *(const float4*)(in + i + 4);
    union { ushort_t u[8]; uint4 v; } r;
    r.u[0] = f2b(a.x); r.u[1] = f2b(a.y); r.u[2] = f2b(a.z); r.u[3] = f2b(a.w);
    r.u[4] = f2b(b.x); r.u[5] = f2b(b.y); r.u[6] = f2b(b.z); r.u[7] = f2b(b.w);
    *(uint4*)(out + i) = r.v;
}

// ------------- transpose + cast: fp32 K x N  ->  bf16 N x K -------------
__global__ __launch_bounds__(256) void transcast(const float* __restrict__ in,
                                                 ushort_t* __restrict__ out,
                                                 int Kd, int Nd) {
    __shared__ float tile[32][33];
    int tx = threadIdx.x & 31, ty = threadIdx.x >> 5;
    int n0 = blockIdx.x * 32, k0 = blockIdx.y * 32;
    for (int j = 0; j < 4; j++)
        tile[ty + 8 * j][tx] = in[(size_t)(k0 + ty + 8 * j) * Nd + n0 + tx];
    __syncthreads();
    for (int j = 0; j < 4; j++)
        out[(size_t)(n0 + ty + 8 * j) * Kd + k0 + tx] = f2b(tile[tx][ty + 8 * j]);
}

// ------------- transpose V region of qkv (bf16) -> vT[b][h][d][s] -------------
__global__ __launch_bounds__(256) void transV(const ushort_t* __restrict__ qkvb,
                                              ushort_t* __restrict__ vT) {
    __shared__ ushort_t tile[32][33];
    int tx = threadIdx.x & 31, ty = threadIdx.x >> 5;
    int s0 = blockIdx.x * 32, d0 = blockIdx.y * 32;
    int bh = blockIdx.z; int b = bh >> 4, h = bh & 15;
    for (int j = 0; j < 4; j++)
        tile[ty + 8 * j][tx] =
            qkvb[(size_t)(b * SEQ + s0 + ty + 8 * j) * QKVN + 2 * HID + h * HD + d0 + tx];
    __syncthreads();
    for (int j = 0; j < 4; j++)
        vT[((size_t)bh * HD + d0 + ty + 8 * j) * SEQ + s0 + tx] = tile[tx][ty + 8 * j];
}

// ------------- GEMM 128x384, BK=32, 3 rotating buffers, wave tile 64x96 -------------
// C(MxN,bf16) = A(MxK,bf16) * BT(NxK,bf16)^T. 8 waves (2x4). Per K-step: 10 asm ds_read
// (4 A-frags + 6 B-frags, 39 FLOP/LDS-byte) + 4 gload_lds (stage kt+2 into buf[(kt+2)%3])
// + vmcnt(4) + barrier + lgkm0 + 24 MFMA + barrier. One barrier pair per step; stage(kt)
// drained at step kt-1's vmcnt(4); WAR safe (target buffer's readers finished at kt-1).
// Granule swizzle g^((r>>1)&3): 8 sequential lanes cover all 32 banks (r9-verified, 0 conflicts).
__global__ __launch_bounds__(512, 1) void gemm3b(const ushort_t* __restrict__ A,
                                                 const ushort_t* __restrict__ BT,
                                                 ushort_t* __restrict__ C,
                                                 int M, int N, int K,
                                                 int scale_cols, float scale) {
    __shared__ __align__(16) ushort_t As[3][128 * 32];  // 24 KB
    __shared__ __align__(16) ushort_t Bs[3][384 * 32];  // 72 KB

    const int t = threadIdx.x;
    const int l = t & 63, w = t >> 6;
    const int wm = w >> 2, wn = w & 3;          // 2 x 4 waves, wave tile 64x96
    const int lr = l & 15, lg = l >> 4;

    // XCD-aware bijective swizzle (grid 512 % 8 == 0)
    const int nwg = gridDim.x;
    const int cpx = nwg >> 3;
    const int swb = (blockIdx.x & 7) * cpx + (blockIdx.x >> 3);
    const int NTN = N / 384;
    const int m0 = (swb / NTN) << 7, n0 = (swb % NTN) * 384;

    const int NKT = K >> 5;                     // K-steps of 32

    f32x4 acc[4][6] = {};

#define STAGE_A(BUF, KT)                                                        \
    do {                                                                        \
        const int r_ = t >> 2, g_ = t & 3;                                      \
        const int gc_ = ((KT) << 5) + ((g_ ^ ((r_ >> 1) & 3)) << 3);            \
        gload_lds16(A + (size_t)(m0 + r_) * K + gc_, &As[BUF][t * 8]);          \
    } while (0)
#define STAGE_B(BUF, KT)                                                        \
    do {                                                                        \
        _Pragma("unroll") for (int sx = 0; sx < 3; sx++) {                      \
            const int i_ = sx * 512 + t;                                        \
            const int r_ = i_ >> 2, g_ = i_ & 3;                                \
            const int gc_ = ((KT) << 5) + ((g_ ^ ((r_ >> 1) & 3)) << 3);        \
            gload_lds16(BT + (size_t)(n0 + r_) * K + gc_, &Bs[BUF][i_ * 8]);    \
        }                                                                       \
    } while (0)

#define STEP(BI, KT)                                                            \
    {                                                                           \
        const int kt2_ = min((KT) + 2, NKT - 1);                                \
        bf16x8 af[4], bfr[6];                                                   \
        lds_char* aB_ = (lds_char*)&As[BI][0];                                  \
        lds_char* bB_ = (lds_char*)&Bs[BI][0];                                  \
        const int co_ = (lg ^ ((lr >> 1) & 3)) << 4;                            \
        _Pragma("unroll") for (int mi = 0; mi < 4; mi++)                        \
            af[mi] = dsr128(aB_ + (wm * 64 + mi * 16 + lr) * 64 + co_);         \
        _Pragma("unroll") for (int nj = 0; nj < 6; nj++)                        \
            bfr[nj] = dsr128(bB_ + (wn * 96 + nj * 16 + lr) * 64 + co_);        \
        STAGE_A(((BI) + 2) % 3, kt2_);                                          \
        STAGE_B(((BI) + 2) % 3, kt2_);                                          \
        VMC4();                                                                 \
        BARX();                                                                 \
        LGKM0();                                                                \
        __builtin_amdgcn_sched_barrier(0);                                      \
        __builtin_amdgcn_s_setprio(1);                                          \
        _Pragma("unroll") for (int mi = 0; mi < 4; mi++)                        \
            _Pragma("unroll") for (int nj = 0; nj < 6; nj++)                    \
                acc[mi][nj] = __builtin_amdgcn_mfma_f32_16x16x32_bf16(          \
                    af[mi], bfr[nj], acc[mi][nj], 0, 0, 0);                     \
        __builtin_amdgcn_s_setprio(0);                                          \
        BARX();                                                                 \
    }

    // prologue: stage tiles 0,1 (8 loads); vmcnt(4) drains tile 0; barrier
    STAGE_A(0, 0); STAGE_B(0, 0);
    STAGE_A(1, 1); STAGE_B(1, 1);
    VMC4();
    BARX();

    const int NFULL = NKT / 3;
    for (int it = 0; it < NFULL; it++) {
        STEP(0, 3 * it);
        STEP(1, 3 * it + 1);
        STEP(2, 3 * it + 2);
    }
    if (NKT % 3 >= 1) STEP(0, NFULL * 3);
    if (NKT % 3 == 2) STEP(1, NFULL * 3 + 1);
    VMC0();

#undef STEP
#undef STAGE_A
#undef STAGE_B

    // epilogue
#pragma unroll
    for (int mi = 0; mi < 4; mi++)
#pragma unroll
        for (int nj = 0; nj < 6; nj++) {
            const int row = m0 + wm * 64 + mi * 16 + lg * 4;
            const int col = n0 + wn * 96 + nj * 16 + lr;
            const float sc = (col < scale_cols) ? scale : 1.0f;
            const f32x4 v = acc[mi][nj];
#pragma unroll
            for (int j = 0; j < 4; j++)
                C[(size_t)(row + j) * N + col] = f2b(v[j] * sc);
        }
}

// ------------- GEMM 128x256, 4-phase/iter, K-split subs, counted vmcnt(6) -------------
// (r9 kernel, used for the out-projection: 256 blocks = 1 exact round)
template <bool OUT_BF16>
__global__ __launch_bounds__(512, 1) void gemm4p(const ushort_t* __restrict__ A,
                                                 const ushort_t* __restrict__ BT,
                                                 void* __restrict__ C,
                                                 int M, int N, int K,
                                                 int scale_cols, float scale) {
    __shared__ __align__(16) ushort_t As[2][2][128 * 32];  // 32 KB
    __shared__ __align__(16) ushort_t Bs[2][2][256 * 32];  // 64 KB

    const int t = threadIdx.x;
    const int l = t & 63, w = t >> 6;
    const int wm = w >> 2, wn = w & 3;          // 2 x 4 waves, wave tile 64x64
    const int lr = l & 15, lg = l >> 4;

    const int nwg = gridDim.x;
    const int cpx = nwg >> 3;
    const int swb = (blockIdx.x & 7) * cpx + (blockIdx.x >> 3);
    const int NTN = N >> 8;
    const int m0 = (swb / NTN) << 7, n0 = (swb % NTN) << 8;

    const int NKT = K >> 6;
    const int NIT = NKT >> 1;

    f32x4 acc[4][4] = {};

#define STAGE_A(BUF, KK, KT)                                                       \
    do {                                                                           \
        const int r_ = t >> 2, g_ = t & 3;                                         \
        const int gc_ = ((KT) << 6) + ((KK) << 5) + ((g_ ^ ((r_ >> 1) & 3)) << 3); \
        gload_lds16(A + (size_t)(m0 + r_) * K + gc_, &As[BUF][KK][t * 8]);         \
    } while (0)
#define STAGE_B(BUF, KK, KT)                                                           \
    do {                                                                               \
        _Pragma("unroll") for (int sx = 0; sx < 2; sx++) {                             \
            const int i_ = sx * 512 + t;                                               \
            const int r_ = i_ >> 2, g_ = i_ & 3;                                       \
            const int gc_ = ((KT) << 6) + ((KK) << 5) + ((g_ ^ ((r_ >> 1) & 3)) << 3); \
            gload_lds16(BT + (size_t)(n0 + r_) * K + gc_, &Bs[BUF][KK][i_ * 8]);       \
        }                                                                              \
    } while (0)

#define PHASE(BUF, KK, STAGES)                                                  \
    {                                                                           \
        bf16x8 af[4], bfr[4];                                                   \
        lds_char* aB_ = (lds_char*)&As[BUF][KK][0];                             \
        lds_char* bB_ = (lds_char*)&Bs[BUF][KK][0];                             \
        const int co_ = (lg ^ ((lr >> 1) & 3)) << 4;                            \
        _Pragma("unroll") for (int mi = 0; mi < 4; mi++)                        \
            af[mi] = dsr128(aB_ + (wm * 64 + mi * 16 + lr) * 64 + co_);         \
        _Pragma("unroll") for (int nn = 0; nn < 4; nn++)                        \
            bfr[nn] = dsr128(bB_ + (wn * 64 + nn * 16 + lr) * 64 + co_);        \
        STAGES;                                                                 \
        VMC6();                                                                 \
        BARX();                                                                 \
        LGKM0();                                                                \
        __builtin_amdgcn_sched_barrier(0);                                      \
        __builtin_amdgcn_s_setprio(1);                                          \
        _Pragma("unroll") for (int mi = 0; mi < 4; mi++)                        \
            _Pragma("unroll") for (int nn = 0; nn < 4; nn++)                    \
                acc[mi][nn] = __builtin_amdgcn_mfma_f32_16x16x32_bf16(          \
                    af[mi], bfr[nn], acc[mi][nn], 0, 0, 0);                     \
        __builtin_amdgcn_s_setprio(0);                                          \
        BARX();                                                                 \
    }

    STAGE_A(0, 0, 0); STAGE_B(0, 0, 0);
    STAGE_A(0, 1, 0); STAGE_B(0, 1, 0);
    STAGE_A(1, 0, 1); STAGE_B(1, 0, 1);
    VMC6();
    BARX();

    for (int it = 0; it < NIT; it++) {
        const int kt1 = 2 * it + 1;
        const int kt2 = min(2 * it + 2, NKT - 1);
        const int kt3 = min(2 * it + 3, NKT - 1);
        PHASE(0, 0, { STAGE_A(1, 1, kt1); STAGE_B(1, 1, kt1); });
        PHASE(0, 1, { STAGE_A(0, 0, kt2); STAGE_B(0, 0, kt2); });
        PHASE(1, 0, { STAGE_A(0, 1, kt2); STAGE_B(0, 1, kt2); });
        PHASE(1, 1, { STAGE_A(1, 0, kt3); STAGE_B(1, 0, kt3); });
    }
    VMC0();

#undef PHASE
#undef STAGE_A
#undef STAGE_B

#pragma unroll
    for (int mi = 0; mi < 4; mi++)
#pragma unroll
        for (int nn = 0; nn < 4; nn++) {
            const int row = m0 + wm * 64 + mi * 16 + lg * 4;
            const int col = n0 + wn * 64 + nn * 16 + lr;
            const float sc = (col < scale_cols) ? scale : 1.0f;
            const f32x4 v = acc[mi][nn];
#pragma unroll
            for (int j = 0; j < 4; j++) {
                if (OUT_BF16)
                    ((ushort_t*)C)[(size_t)(row + j) * N + col] = f2b(v[j] * sc);
                else
                    ((float*)C)[(size_t)(row + j) * N + col] = v[j] * sc;
            }
        }
}

// ------------- flash attention v3: 8 waves x 16 q-rows, paired q-tiles, dbuf gload_lds -------------
__global__ __launch_bounds__(512, 1) void attn_fwd3(const ushort_t* __restrict__ qkvb,
                                                    const ushort_t* __restrict__ vT,
                                                    ushort_t* __restrict__ attnb) {
    __shared__ __align__(16) ushort_t Ks[2][64 * 128];
    __shared__ __align__(16) ushort_t Vs[2][128 * 64];
    __shared__ __align__(16) ushort_t Ps[8][16 * 64];

    const int t = threadIdx.x;
    const int l = t & 63, w = t >> 6;
    const int lr = l & 15, lg = l >> 4;
    const int pr = blockIdx.x, h = blockIdx.y, b = blockIdx.z;

    const ushort_t* kg = qkvb + (size_t)(b * SEQ) * QKVN + HID + h * HD;
    const ushort_t* vg = vT + (size_t)(b * NH + h) * HD * SEQ;

    char* PsB = (char*)Ps[w];
    const int pssz = ((lr & 7) ^ ((lr >> 3) << 1)) << 4;

    const int kcA = 2 * w, kcB = 2 * w + 1;
    const int krA = 8 * w + (l >> 4), krB = krA + 4;
    const int kcolA = ((l & 15) ^ (l >> 4)) << 3;
    const int kcolB = ((l & 15) ^ (4 + (l >> 4))) << 3;
    const int vrA = 16 * w + (l >> 3), vrB = vrA + 8;
    const int vcol = ((l & 7) ^ (l >> 3)) << 3;

    for (int seg = 0; seg < 2; seg++) {
        const int qt = (seg == 0) ? pr : 15 - pr;
        const int q0 = qt * QB;
        const int q0w = q0 + w * 16;
        const int NT = (q0 + QB) / KVB;

        bf16x8 qf[4];
        {
            const ushort_t* qb = qkvb + (size_t)(b * SEQ + q0w + lr) * QKVN + h * HD + lg * 8;
#pragma unroll
            for (int kc = 0; kc < 4; kc++) qf[kc] = *(const bf16x8*)(qb + kc * 32);
        }
        f32x4 o[8] = {};
        float m[4] = {-3e38f, -3e38f, -3e38f, -3e38f};
        float ls[4] = {0.f, 0.f, 0.f, 0.f};

        __syncthreads();
        gload_lds16(kg + (size_t)krA * QKVN + kcolA, &Ks[0][kcA * 512 + l * 8]);
        gload_lds16(kg + (size_t)krB * QKVN + kcolB, &Ks[0][kcB * 512 + l * 8]);
        gload_lds16(vg + (size_t)vrA * SEQ + vcol,   &Vs[0][kcA * 512 + l * 8]);
        gload_lds16(vg + (size_t)vrB * SEQ + vcol,   &Vs[0][kcB * 512 + l * 8]);

        for (int kt = 0; kt < NT; kt++) {
            const int kv0 = kt * KVB;
            __syncthreads();
            if (kt + 1 < NT) {
                const int nb = (kt + 1) & 1;
                const int nkv = kv0 + KVB;
                gload_lds16(kg + (size_t)(nkv + krA) * QKVN + kcolA, &Ks[nb][kcA * 512 + l * 8]);
                gload_lds16(kg + (size_t)(nkv + krB) * QKVN + kcolB, &Ks[nb][kcB * 512 + l * 8]);
                gload_lds16(vg + (size_t)vrA * SEQ + nkv + vcol,     &Vs[nb][kcA * 512 + l * 8]);
                gload_lds16(vg + (size_t)vrB * SEQ + nkv + vcol,     &Vs[nb][kcB * 512 + l * 8]);
            }
            if (kv0 > q0w + 15) continue;
            const char* KsB = (const char*)Ks[kt & 1];
            const char* VsB = (const char*)Vs[kt & 1];

            f32x4 s[4];
            const int rs = (lr & 7) << 4;
#pragma unroll
            for (int nf = 0; nf < 4; nf++) {
                const int r = nf * 16 + lr;
                s[nf] = (f32x4){0.f, 0.f, 0.f, 0.f};
#pragma unroll
                for (int kc = 0; kc < 4; kc++) {
                    bf16x8 kf = *(const bf16x8*)(KsB + r * 256 + ((kc * 64 + lg * 16) ^ rs));
                    s[nf] = __builtin_amdgcn_mfma_f32_16x16x32_bf16(qf[kc], kf, s[nf], 0, 0, 0);
                }
            }

            const bool diag = (kv0 + 63 > q0w);
            float tm[4];
#pragma unroll
            for (int j = 0; j < 4; j++) {
                if (diag) {
                    const int qpos = q0w + lg * 4 + j;
#pragma unroll
                    for (int nf = 0; nf < 4; nf++)
                        if (kv0 + nf * 16 + lr > qpos) s[nf][j] = -3e38f;
                }
                tm[j] = fmaxf(fmaxf(s[0][j], s[1][j]), fmaxf(s[2][j], s[3][j]));
#pragma unroll
                for (int mk = 1; mk < 16; mk <<= 1)
                    tm[j] = fmaxf(tm[j], __shfl_xor(tm[j], mk, 64));
            }

            float grow = fmaxf(fmaxf(tm[0] - m[0], tm[1] - m[1]),
                               fmaxf(tm[2] - m[2], tm[3] - m[3]));
            if (!__all(grow <= 8.0f)) {
#pragma unroll
                for (int j = 0; j < 4; j++) {
                    const float mn = fmaxf(m[j], tm[j]);
                    const float fac = exp2f((m[j] - mn) * 1.44269504f);
                    m[j] = mn; ls[j] *= fac;
#pragma unroll
                    for (int nf2 = 0; nf2 < 8; nf2++) o[nf2][j] *= fac;
                }
            }

#pragma unroll
            for (int j = 0; j < 4; j++) {
                const int row = lg * 4 + j;
                const int rsz = ((row & 7) ^ ((row >> 3) << 1)) << 4;
                float psum = 0.f;
#pragma unroll
                for (int nf = 0; nf < 4; nf++) {
                    float p = exp2f((s[nf][j] - m[j]) * 1.44269504f);
                    psum += p;
                    union { float f; unsigned u; } cv; cv.f = p;
                    *(ushort_t*)(PsB + row * 128 + ((nf * 32 + lr * 2) ^ rsz)) = (ushort_t)(cv.u >> 16);
                }
                ls[j] += psum;
            }

            bf16x8 pa0 = *(const bf16x8*)(PsB + lr * 128 + ((lg * 16) ^ pssz));
            bf16x8 pa1 = *(const bf16x8*)(PsB + lr * 128 + ((64 + lg * 16) ^ pssz));
#pragma unroll
            for (int nf2 = 0; nf2 < 8; nf2++) {
                const int vr2 = nf2 * 16 + lr;
                bf16x8 vb0 = *(const bf16x8*)(VsB + vr2 * 128 + ((lg * 16) ^ rs));
                bf16x8 vb1 = *(const bf16x8*)(VsB + vr2 * 128 + ((64 + lg * 16) ^ rs));
                o[nf2] = __builtin_amdgcn_mfma_f32_16x16x32_bf16(pa0, vb0, o[nf2], 0, 0, 0);
                o[nf2] = __builtin_amdgcn_mfma_f32_16x16x32_bf16(pa1, vb1, o[nf2], 0, 0, 0);
            }
        }

        float inv[4];
#pragma unroll
        for (int j = 0; j < 4; j++) {
            float sum = ls[j];
#pragma unroll
            for (int mk = 1; mk < 16; mk <<= 1) sum += __shfl_xor(sum, mk, 64);
            inv[j] = 1.0f / sum;
        }
        ushort_t* ob = attnb + (size_t)(b * SEQ + q0w) * HID + h * HD;
#pragma unroll
        for (int nf2 = 0; nf2 < 8; nf2++)
#pragma unroll
            for (int j = 0; j < 4; j++)
                ob[(size_t)(lg * 4 + j) * HID + nf2 * 16 + lr] = f2b(o[nf2][j] * inv[j]);
    }
}

extern "C" void kernel_launch(void* const* d_in, const int* in_sizes, int n_in,
                              void* d_out, int out_size, void* d_ws, size_t ws_size,
                              hipStream_t stream) {
    const float* x     = (const float*)d_in[0];
    const float* w_qkv = (const float*)d_in[1];
    const float* w_out = (const float*)d_in[2];
    float* out = (float*)d_out;

    char* ws = (char*)d_ws;
    ushort_t* xb    = (ushort_t*)(ws);                 // 4096x2048 bf16
    ushort_t* wqkvT = (ushort_t*)(ws + 16777216);      // 6144x2048 bf16
    ushort_t* woutT = (ushort_t*)(ws + 41943040);      // 2048x2048 bf16
    ushort_t* qkvb  = (ushort_t*)(ws + 50331648);      // 4096x6144 bf16
    ushort_t* vT    = (ushort_t*)(ws + 100663296);     // [b][h][d][s] bf16
    ushort_t* attnb = (ushort_t*)(ws + 117440512);     // 4096x2048 bf16

    const int M = 2 * SEQ;  // 4096

    castbf<<<(M * HID) / (256 * 8), 256, 0, stream>>>(x, xb, M * HID);
    transcast<<<dim3(QKVN / 32, HID / 32), 256, 0, stream>>>(w_qkv, wqkvT, HID, QKVN);
    transcast<<<dim3(HID / 32, HID / 32), 256, 0, stream>>>(w_out, woutT, HID, HID);

    // qkv = x @ w_qkv, Q pre-scaled; 128x384 3-buffer GEMM, 512 blocks = 2 exact rounds
    gemm3b<<<(M / 128) * (QKVN / 384), 512, 0, stream>>>(
        xb, wqkvT, qkvb, M, QKVN, HID, HID, 0.08838834764831845f);

    transV<<<dim3(SEQ / 32, HD / 32, 2 * NH), 256, 0, stream>>>(qkvb, vT);

    attn_fwd3<<<dim3(8, NH, 2), 512, 0, stream>>>(qkvb, vT, attnb);

    // out = attn @ w_out; 128x256 4-phase GEMM, 256 blocks (full GPU, 1 round)
    gemm4p<false><<<(M / 128) * (HID / 256), 512, 0, stream>>>(
        attnb, woutT, out, M, HID, HID, 0, 1.0f);
}